// Round 8
// baseline (735.238 us; speedup 1.0000x reference)
//
#include <hip/hip_runtime.h>

#define NN 50000
#define EE 640000
#define GG 16
#define N64 (NN*64)

static inline int cdiv(int a,int b){return (a+b-1)/b;}

typedef __attribute__((ext_vector_type(8))) short bfrag;   // 8 bf16 (4 VGPR)
typedef __attribute__((ext_vector_type(4))) float ffrag;   // mfma accumulator
typedef __attribute__((ext_vector_type(2))) float f32x2;

__device__ __forceinline__ float lrelu(float x){ return x>0.f? x : 0.2f*x; }
__device__ __forceinline__ unsigned fenc(float f){
  unsigned u=__float_as_uint(f);
  return (u&0x80000000u)? ~u : (u|0x80000000u);
}
__device__ __forceinline__ float bf2f(unsigned short u){ return __uint_as_float(((unsigned)u)<<16); }
__device__ __forceinline__ unsigned short f2bf(float f){
  unsigned u=__float_as_uint(f);
  u += 0x7FFFu + ((u>>16)&1u);
  return (unsigned short)(u>>16);
}
// OCP e4m3 helpers (gfx950 hw cvt)
__device__ __forceinline__ unsigned char f2f8(float f){
  return (unsigned char)(__builtin_amdgcn_cvt_pk_fp8_f32(f,f,0,false)&0xff);
}
__device__ __forceinline__ void f8x4(unsigned u, float& e0,float& e1,float& e2,float& e3){
  f32x2 lo=__builtin_amdgcn_cvt_pk_f32_fp8((int)u,false);
  f32x2 hi=__builtin_amdgcn_cvt_pk_f32_fp8((int)u,true);
  e0=lo.x; e1=lo.y; e2=hi.x; e3=hi.y;
}
__device__ __forceinline__ float f8one(unsigned b){
  f32x2 lo=__builtin_amdgcn_cvt_pk_f32_fp8((int)b,false);
  return lo.x;
}
__device__ __forceinline__ float dot4f8(unsigned a, unsigned b){
  f32x2 al=__builtin_amdgcn_cvt_pk_f32_fp8((int)a,false);
  f32x2 ah=__builtin_amdgcn_cvt_pk_f32_fp8((int)a,true);
  f32x2 bl=__builtin_amdgcn_cvt_pk_f32_fp8((int)b,false);
  f32x2 bh=__builtin_amdgcn_cvt_pk_f32_fp8((int)b,true);
  return al.x*bl.x+al.y*bl.y+ah.x*bh.x+ah.y*bh.y;
}

__global__ void zero_kernel(unsigned* p, int n){
  int i=blockIdx.x*blockDim.x+threadIdx.x;
  if(i<n) p[i]=0u;
}

__global__ void hist_kernel(const int* __restrict__ dst, int* __restrict__ cnt){
  int e=blockIdx.x*blockDim.x+threadIdx.x;
  if(e<EE) atomicAdd(&cnt[dst[e]],1);
}

__global__ __launch_bounds__(1024) void scan1_kernel(const int* __restrict__ cnt,
    int* __restrict__ rowptr, int* __restrict__ bsum){
  __shared__ int wsum[16];
  int t=threadIdx.x, b=blockIdx.x;
  int i=b*1024+t;
  int v=(i<NN)?cnt[i]:0;
  int lane=t&63, w=t>>6;
  int inc=v;
  #pragma unroll
  for(int o=1;o<64;o<<=1){ int u=__shfl_up(inc,o,64); if(lane>=o) inc+=u; }
  if(lane==63) wsum[w]=inc;
  __syncthreads();
  if(t<16){
    int s=wsum[t];
    #pragma unroll
    for(int o=1;o<16;o<<=1){ int u=__shfl_up(s,o,16); if(t>=o) s+=u; }
    wsum[t]=s;
  }
  __syncthreads();
  int woff=(w>0)?wsum[w-1]:0;
  if(i<NN) rowptr[i]=woff+inc-v;
  if(t==1023) bsum[b]=wsum[15];
}

__global__ void scan2_kernel(const int* __restrict__ bsum, int* __restrict__ boff, int* __restrict__ rowptr, int nb){
  int t=threadIdx.x;
  int v=(t<nb)?bsum[t]:0;
  int inc=v;
  #pragma unroll
  for(int o=1;o<64;o<<=1){ int u=__shfl_up(inc,o,64); if(t>=o) inc+=u; }
  if(t<nb) boff[t]=inc-v;
  if(t==63) rowptr[NN]=inc;
}

__global__ void scan3_kernel(int* __restrict__ rowptr, const int* __restrict__ boff,
                             const int* __restrict__ cnt, float* __restrict__ invdeg){
  int i=blockIdx.x*blockDim.x+threadIdx.x;
  if(i<NN){
    rowptr[i]+=boff[i>>10];
    invdeg[i]=1.f/fmaxf((float)cnt[i],1.f);
  }
}

// CSR fill: ONE int2 scatter-store per edge (src,dst packed) -> half the dirty lines
__global__ void fill_kernel(const int* __restrict__ src, const int* __restrict__ dst,
                            const int* __restrict__ rowptr, int* __restrict__ fillp,
                            int2* __restrict__ sd){
  int e=blockIdx.x*blockDim.x+threadIdx.x;
  if(e>=EE) return;
  int d=dst[e];
  int p=rowptr[d]+atomicAdd(&fillp[d],1);
  sd[p]=make_int2(src[e],d);
}

__global__ void cvtx_kernel(const float* __restrict__ x, unsigned short* __restrict__ xb){
  int i=blockIdx.x*blockDim.x+threadIdx.x;
  if(i>=NN*32) return;
  float4 v=*(const float4*)(x+(size_t)i*4);
  ushort4 o; o.x=f2bf(v.x); o.y=f2bf(v.y); o.z=f2bf(v.z); o.w=f2bf(v.w);
  *(ushort4*)(xb+(size_t)i*4)=o;
}

// weight prep: Wt[n][k]=W[k][n] bf16, all segments + bias packs
__global__ void prep_kernel(
    const float* __restrict__ g1W, const float* __restrict__ g2W,
    const float* __restrict__ giW1, const float* __restrict__ giW2,
    const float* __restrict__ s1Wl, const float* __restrict__ s1Wr,
    const float* __restrict__ s2Wl, const float* __restrict__ s2Wr,
    const float* __restrict__ Wq, const float* __restrict__ Wk,
    const float* __restrict__ Wv, const float* __restrict__ Ws,
    const float* __restrict__ ecW1, const float* __restrict__ ecW2,
    const float* __restrict__ bq, const float* __restrict__ bk, const float* __restrict__ eb1,
    unsigned short* __restrict__ wt, float* __restrict__ bqk, float* __restrict__ bPQ){
  int i=blockIdx.x*blockDim.x+threadIdx.x;
  if(i<32768){ int n=i>>7,k=i&127; wt[i]=f2bf(g1W[k*256+n]); return; } i-=32768;
  if(i<16384){ int n=i>>6,k=i&63; wt[32768+i]=f2bf(g2W[k*256+n]); return; } i-=16384;
  if(i<4096){ int n=i>>6,k=i&63; wt[49152+i]=f2bf(giW1[k*64+n]); return; } i-=4096;
  if(i<4096){ int n=i>>6,k=i&63; wt[53248+i]=f2bf(giW2[k*64+n]); return; } i-=4096;
  if(i<8192){ int n=i>>7,k=i&127; float v=(k<64)?s1Wl[k*64+n]:s1Wr[(k-64)*64+n];
              wt[57344+i]=f2bf(v); return; } i-=8192;
  if(i<8192){ int n=i>>7,k=i&127; float v=(k<64)?s2Wl[k*64+n]:s2Wr[(k-64)*64+n];
              wt[65536+i]=f2bf(v); return; } i-=8192;
  if(i<32768){ int n=i>>6,k=i&63; float v=(n<256)?Wq[k*256+n]:Wk[k*256+(n-256)];
               wt[73728+i]=f2bf(v); return; } i-=32768;
  if(i<16384){ int n=i>>6,k=i&63; wt[106496+i]=f2bf(Wv[k*256+n]); return; } i-=16384;
  if(i<4096){ int n=i>>6,k=i&63; wt[122880+i]=f2bf(Ws[k*64+n]); return; } i-=4096;
  if(i<8192){ int n=i>>6,k=i&63;
              float v=(n<64)?(ecW1[k*64+n]-ecW1[(64+k)*64+n]):ecW1[(64+k)*64+(n-64)];
              wt[126976+i]=f2bf(v); return; } i-=8192;
  if(i<4096){ int n=i>>6,k=i&63; wt[135168+i]=f2bf(ecW2[k*64+n]); return; } i-=4096;
  if(i<640){
    if(i<256) bqk[i]=bq[i];
    else if(i<512) bqk[i]=bk[i-256];
    else { int j=i-512; bPQ[j]=(j<64)?eb1[j]:0.f; }
  }
}

// bf16 MFMA GEMM with LDS A-staging: C[64x64 tile] = A[M,K]bf16 @ Wt[N,K]bf16^T (+bias)(relu)
template<int K>
__global__ __launch_bounds__(256) void mgemm_kernel(
    const unsigned short* __restrict__ A, const unsigned short* __restrict__ Wt,
    const float* __restrict__ bias,
    float* __restrict__ Cf, unsigned short* __restrict__ Cb, unsigned char* __restrict__ C8,
    int ldc, int relu_flag, int c8mode,
    const float* __restrict__ a_s, const float* __restrict__ a_d,
    float* __restrict__ lsO, float* __restrict__ ldO){
  __shared__ float lsP[2][4][64];
  __shared__ unsigned short As[64][K+8];
  const int m0=blockIdx.x*64;
  const int tid=threadIdx.x;
  #pragma unroll
  for(int it=0; it<K/32; ++it){
    int c = it*256 + tid;
    int row = c/(K/8), col8 = c%(K/8);
    int grow = m0+row; if(grow>=NN) grow=NN-1;
    *(bfrag*)&As[row][col8*8] = *(const bfrag*)(A+(size_t)grow*K+col8*8);
  }
  __syncthreads();
  const int w=tid>>6, l=tid&63, lo=l&15, quad=l>>4;
  const int colg=blockIdx.y*64 + w*16 + lo;
  const unsigned short* wrow=Wt+(size_t)colg*K+quad*8;
  ffrag acc[4];
  #pragma unroll
  for(int t=0;t<4;t++) acc[t]=(ffrag){0.f,0.f,0.f,0.f};
  #pragma unroll
  for(int kc=0;kc<K;kc+=32){
    bfrag b=*(const bfrag*)(wrow+kc);
    #pragma unroll
    for(int t=0;t<4;t++){
      bfrag a=*(const bfrag*)(&As[t*16+lo][kc+quad*8]);
      acc[t]=__builtin_amdgcn_mfma_f32_16x16x32_bf16(a,b,acc[t],0,0,0);
    }
  }
  float bv=bias?bias[colg]:0.f;
  float asv=0.f,adv=0.f;
  if(lsO){ asv=a_s[colg]; adv=a_d[colg]; }
  #pragma unroll
  for(int t=0;t<4;t++){
    #pragma unroll
    for(int r=0;r<4;r++){
      float v=acc[t][r]+bv;
      if(relu_flag) v=fmaxf(v,0.f);
      int row=m0+t*16+quad*4+r;
      if(row<NN){
        if(Cf) Cf[(size_t)row*ldc+colg]=v;
        if(Cb) Cb[(size_t)row*ldc+colg]=f2bf(v);
        if(C8){
          size_t idx;
          if(c8mode==1)      idx=(size_t)row*ldc + (((colg&63)<<2)|(colg>>6));
          else if(c8mode==2) idx=(size_t)((colg<64)?0:N64) + (size_t)row*64 + (colg&63);
          else               idx=(size_t)row*ldc + colg;
          C8[idx]=f2f8(v);
        }
      }
      if(lsO){
        float ps=v*asv, pd=v*adv;
        #pragma unroll
        for(int o=1;o<16;o<<=1){ ps+=__shfl_xor(ps,o,16); pd+=__shfl_xor(pd,o,16); }
        if(lo==0){ int lr=t*16+quad*4+r; lsP[0][w][lr]=ps; lsP[1][w][lr]=pd; }
      }
    }
  }
  if(lsO){
    __syncthreads();
    if(tid<64){
      int row=m0+tid;
      if(row<NN){
        lsO[(size_t)row*4+blockIdx.y]=lsP[0][0][tid]+lsP[0][1][tid]+lsP[0][2][tid]+lsP[0][3][tid];
        ldO[(size_t)row*4+blockIdx.y]=lsP[1][0][tid]+lsP[1][1][tid]+lsP[1][2][tid]+lsP[1][3][tid];
      }
    }
  }
}

// GAT edge exps: eE[j] = exp(lrelu(ls[src]+ld[dst])), one thread per edge (computed ONCE).
__global__ void gat_exp_kernel(const int2* __restrict__ sd,
    const float* __restrict__ ls4, const float* __restrict__ ld4, float* __restrict__ eE){
  int j=blockIdx.x*blockDim.x+threadIdx.x;
  if(j>=EE) return;
  int2 p=sd[j];
  const float4 a=*(const float4*)(ls4+(size_t)4*p.x);
  const float4 b=*(const float4*)(ld4+(size_t)4*p.y);
  *(float4*)(eE+(size_t)4*j)=make_float4(
    __expf(lrelu(a.x+b.x)),__expf(lrelu(a.y+b.y)),
    __expf(lrelu(a.z+b.z)),__expf(lrelu(a.w+b.w)));
}

// single-pass GAT: 1 WAVE PER NODE (4 nodes/block), unroll-8/4/tail, fp8 h gather.
__global__ __launch_bounds__(256) void gat1p_kernel(const unsigned char* __restrict__ h8,
    const int* __restrict__ rowptr, const int2* __restrict__ sd,
    const float* __restrict__ eE,
    const float* __restrict__ ls4, const float* __restrict__ ld4,
    const float* __restrict__ bias, unsigned short* __restrict__ outb,
    unsigned char* __restrict__ out8){
  int w=threadIdx.x>>6, lane=threadIdx.x&63;
  int n=blockIdx.x*4+w;
  if(n>=NN) return;
  int r0=rowptr[n], r1=rowptr[n+1];
  const float4 ldv=*(const float4*)(ld4+(size_t)4*n);
  const float4 lsv=*(const float4*)(ls4+(size_t)4*n);
  float z0=__expf(lrelu(lsv.x+ldv.x)), z1=__expf(lrelu(lsv.y+ldv.y));
  float z2=__expf(lrelu(lsv.z+ldv.z)), z3=__expf(lrelu(lsv.w+ldv.w));
  float h0,h1,h2,h3;
  f8x4(*(const unsigned*)(h8+(size_t)n*256+lane*4),h0,h1,h2,h3);
  float a0=z0*h0, a1=z1*h1, a2=z2*h2, a3=z3*h3;
  int j=r0;
  for(; j+7<r1; j+=8){
    int s0=sd[j].x,   s1=sd[j+1].x, s2=sd[j+2].x, s3=sd[j+3].x;
    int s4=sd[j+4].x, s5=sd[j+5].x, s6=sd[j+6].x, s7=sd[j+7].x;
    const float4 E0=*(const float4*)(eE+(size_t)4*j);
    const float4 E1=*(const float4*)(eE+(size_t)4*(j+1));
    const float4 E2=*(const float4*)(eE+(size_t)4*(j+2));
    const float4 E3=*(const float4*)(eE+(size_t)4*(j+3));
    const float4 E4=*(const float4*)(eE+(size_t)4*(j+4));
    const float4 E5=*(const float4*)(eE+(size_t)4*(j+5));
    const float4 E6=*(const float4*)(eE+(size_t)4*(j+6));
    const float4 E7=*(const float4*)(eE+(size_t)4*(j+7));
    unsigned u0=*(const unsigned*)(h8+(size_t)s0*256+lane*4);
    unsigned u1=*(const unsigned*)(h8+(size_t)s1*256+lane*4);
    unsigned u2=*(const unsigned*)(h8+(size_t)s2*256+lane*4);
    unsigned u3=*(const unsigned*)(h8+(size_t)s3*256+lane*4);
    unsigned u4=*(const unsigned*)(h8+(size_t)s4*256+lane*4);
    unsigned u5=*(const unsigned*)(h8+(size_t)s5*256+lane*4);
    unsigned u6=*(const unsigned*)(h8+(size_t)s6*256+lane*4);
    unsigned u7=*(const unsigned*)(h8+(size_t)s7*256+lane*4);
    float p0,p1,p2,p3;
    f8x4(u0,p0,p1,p2,p3); a0+=E0.x*p0; a1+=E0.y*p1; a2+=E0.z*p2; a3+=E0.w*p3;
    f8x4(u1,p0,p1,p2,p3); a0+=E1.x*p0; a1+=E1.y*p1; a2+=E1.z*p2; a3+=E1.w*p3;
    f8x4(u2,p0,p1,p2,p3); a0+=E2.x*p0; a1+=E2.y*p1; a2+=E2.z*p2; a3+=E2.w*p3;
    f8x4(u3,p0,p1,p2,p3); a0+=E3.x*p0; a1+=E3.y*p1; a2+=E3.z*p2; a3+=E3.w*p3;
    f8x4(u4,p0,p1,p2,p3); a0+=E4.x*p0; a1+=E4.y*p1; a2+=E4.z*p2; a3+=E4.w*p3;
    f8x4(u5,p0,p1,p2,p3); a0+=E5.x*p0; a1+=E5.y*p1; a2+=E5.z*p2; a3+=E5.w*p3;
    f8x4(u6,p0,p1,p2,p3); a0+=E6.x*p0; a1+=E6.y*p1; a2+=E6.z*p2; a3+=E6.w*p3;
    f8x4(u7,p0,p1,p2,p3); a0+=E7.x*p0; a1+=E7.y*p1; a2+=E7.z*p2; a3+=E7.w*p3;
    z0+=((E0.x+E1.x)+(E2.x+E3.x))+((E4.x+E5.x)+(E6.x+E7.x));
    z1+=((E0.y+E1.y)+(E2.y+E3.y))+((E4.y+E5.y)+(E6.y+E7.y));
    z2+=((E0.z+E1.z)+(E2.z+E3.z))+((E4.z+E5.z)+(E6.z+E7.z));
    z3+=((E0.w+E1.w)+(E2.w+E3.w))+((E4.w+E5.w)+(E6.w+E7.w));
  }
  for(; j+3<r1; j+=4){
    int s0=sd[j].x, s1=sd[j+1].x, s2=sd[j+2].x, s3=sd[j+3].x;
    const float4 E0=*(const float4*)(eE+(size_t)4*j);
    const float4 E1=*(const float4*)(eE+(size_t)4*(j+1));
    const float4 E2=*(const float4*)(eE+(size_t)4*(j+2));
    const float4 E3=*(const float4*)(eE+(size_t)4*(j+3));
    unsigned u0=*(const unsigned*)(h8+(size_t)s0*256+lane*4);
    unsigned u1=*(const unsigned*)(h8+(size_t)s1*256+lane*4);
    unsigned u2=*(const unsigned*)(h8+(size_t)s2*256+lane*4);
    unsigned u3=*(const unsigned*)(h8+(size_t)s3*256+lane*4);
    float p0,p1,p2,p3;
    f8x4(u0,p0,p1,p2,p3); a0+=E0.x*p0; a1+=E0.y*p1; a2+=E0.z*p2; a3+=E0.w*p3;
    f8x4(u1,p0,p1,p2,p3); a0+=E1.x*p0; a1+=E1.y*p1; a2+=E1.z*p2; a3+=E1.w*p3;
    f8x4(u2,p0,p1,p2,p3); a0+=E2.x*p0; a1+=E2.y*p1; a2+=E2.z*p2; a3+=E2.w*p3;
    f8x4(u3,p0,p1,p2,p3); a0+=E3.x*p0; a1+=E3.y*p1; a2+=E3.z*p2; a3+=E3.w*p3;
    z0+=(E0.x+E1.x)+(E2.x+E3.x); z1+=(E0.y+E1.y)+(E2.y+E3.y);
    z2+=(E0.z+E1.z)+(E2.z+E3.z); z3+=(E0.w+E1.w)+(E2.w+E3.w);
  }
  for(; j<r1; j++){
    int s0=sd[j].x;
    const float4 E0=*(const float4*)(eE+(size_t)4*j);
    unsigned u0=*(const unsigned*)(h8+(size_t)s0*256+lane*4);
    float p0,p1,p2,p3; f8x4(u0,p0,p1,p2,p3);
    z0+=E0.x; z1+=E0.y; z2+=E0.z; z3+=E0.w;
    a0+=E0.x*p0; a1+=E0.y*p1; a2+=E0.z*p2; a3+=E0.w*p3;
  }
  float r=0.25f*(a0/(z0+1e-16f)+a1/(z1+1e-16f)+a2/(z2+1e-16f)+a3/(z3+1e-16f))+bias[lane];
  float rr=fmaxf(r,0.f);
  outb[(size_t)n*64+lane]=f2bf(rr);
  if(out8) out8[(size_t)n*64+lane]=f2f8(rr);
}

// GIN: self(bf16) + sum of neighbors (fp8 L2-resident gather), unroll 4
__global__ __launch_bounds__(256) void agg_kernel(const unsigned short* __restrict__ xin,
    const unsigned char* __restrict__ xin8,
    const int* __restrict__ rowptr, const int2* __restrict__ sd,
    unsigned short* __restrict__ out){
  int n=blockIdx.x*4+(threadIdx.x>>6);
  int lane=threadIdx.x&63;
  if(n>=NN) return;
  int r0=rowptr[n], r1=rowptr[n+1];
  float acc=bf2f(xin[(size_t)n*64+lane]);
  int j=r0;
  for(; j+3<r1; j+=4){
    int s0=sd[j].x, s1=sd[j+1].x, s2=sd[j+2].x, s3=sd[j+3].x;
    unsigned b0=xin8[(size_t)s0*64+lane];
    unsigned b1=xin8[(size_t)s1*64+lane];
    unsigned b2=xin8[(size_t)s2*64+lane];
    unsigned b3=xin8[(size_t)s3*64+lane];
    acc+=(f8one(b0)+f8one(b1))+(f8one(b2)+f8one(b3));
  }
  for(; j<r1; j++) acc+=f8one(xin8[(size_t)sd[j].x*64+lane]);
  out[(size_t)n*64+lane]=f2bf(acc);
}

// SAGE staging: out128b[n]=[mean_neigh(fp8 gather), self(bf16)] bf16, unroll 4
__global__ __launch_bounds__(256) void agg2_kernel(const unsigned short* __restrict__ xin,
    const unsigned char* __restrict__ xin8,
    const int* __restrict__ rowptr, const int2* __restrict__ sd,
    const float* __restrict__ invdeg, unsigned short* __restrict__ out128b){
  int n=blockIdx.x*4+(threadIdx.x>>6);
  int lane=threadIdx.x&63;
  if(n>=NN) return;
  int r0=rowptr[n], r1=rowptr[n+1];
  float acc=0.f;
  int j=r0;
  for(; j+3<r1; j+=4){
    int s0=sd[j].x, s1=sd[j+1].x, s2=sd[j+2].x, s3=sd[j+3].x;
    unsigned b0=xin8[(size_t)s0*64+lane];
    unsigned b1=xin8[(size_t)s1*64+lane];
    unsigned b2=xin8[(size_t)s2*64+lane];
    unsigned b3=xin8[(size_t)s3*64+lane];
    acc+=(f8one(b0)+f8one(b1))+(f8one(b2)+f8one(b3));
  }
  for(; j<r1; j++) acc+=f8one(xin8[(size_t)sd[j].x*64+lane]);
  out128b[(size_t)n*128+lane]=f2bf(acc*invdeg[n]);
  out128b[(size_t)n*128+64+lane]=xin[(size_t)n*64+lane];
}

// TR pass1 (edge-parallel SDDMM): qk8 [N,512] fp8 (q|k head-major); stores EXP of logits.
__global__ __launch_bounds__(256) void tr_pass1_kernel(const int2* __restrict__ sd,
    const unsigned char* __restrict__ qk8, float* __restrict__ lg){
  int e=blockIdx.x*16+(threadIdx.x>>4);
  int t=threadIdx.x&15;
  if(e>=EE) return;
  int2 p=sd[e];
  const unsigned char* qd=qk8+(size_t)p.y*512+t*4;
  const unsigned char* ks=qk8+(size_t)p.x*512+256+t*4;
  unsigned ku0=*(const unsigned*)(ks);
  unsigned ku1=*(const unsigned*)(ks+64);
  unsigned ku2=*(const unsigned*)(ks+128);
  unsigned ku3=*(const unsigned*)(ks+192);
  unsigned qu0=*(const unsigned*)(qd);
  unsigned qu1=*(const unsigned*)(qd+64);
  unsigned qu2=*(const unsigned*)(qd+128);
  unsigned qu3=*(const unsigned*)(qd+192);
  float v0=dot4f8(ku0,qu0);
  float v1=dot4f8(ku1,qu1);
  float v2=dot4f8(ku2,qu2);
  float v3=dot4f8(ku3,qu3);
  #pragma unroll
  for(int o=1;o<16;o<<=1){
    v0+=__shfl_xor(v0,o,16); v1+=__shfl_xor(v1,o,16);
    v2+=__shfl_xor(v2,o,16); v3+=__shfl_xor(v3,o,16);
  }
  if(t==0)
    *(float4*)(lg+(size_t)4*e)=make_float4(__expf(v0*0.125f),__expf(v1*0.125f),
                                           __expf(v2*0.125f),__expf(v3*0.125f));
}

// TR pass2: 1 WAVE PER NODE (4 nodes/block), unroll-8/4/tail; fp8 v-gather + skip + relu
__global__ __launch_bounds__(256) void tr_pass2_kernel(const int* __restrict__ rowptr, const int2* __restrict__ sd,
    const float* __restrict__ lg,
    const unsigned char* __restrict__ v8, const float* __restrict__ skip, unsigned short* __restrict__ x5b){
  int w=threadIdx.x>>6, lane=threadIdx.x&63;
  int n=blockIdx.x*4+w;
  if(n>=NN) return;
  int r0=rowptr[n], r1=rowptr[n+1];
  float z0=0.f,z1=0.f,z2=0.f,z3=0.f;
  float a0=0.f,a1=0.f,a2=0.f,a3=0.f;
  int j=r0;
  for(; j+7<r1; j+=8){
    int s0=sd[j].x,   s1=sd[j+1].x, s2=sd[j+2].x, s3=sd[j+3].x;
    int s4=sd[j+4].x, s5=sd[j+5].x, s6=sd[j+6].x, s7=sd[j+7].x;
    const float4 E0=*(const float4*)(lg+(size_t)4*j);
    const float4 E1=*(const float4*)(lg+(size_t)4*(j+1));
    const float4 E2=*(const float4*)(lg+(size_t)4*(j+2));
    const float4 E3=*(const float4*)(lg+(size_t)4*(j+3));
    const float4 E4=*(const float4*)(lg+(size_t)4*(j+4));
    const float4 E5=*(const float4*)(lg+(size_t)4*(j+5));
    const float4 E6=*(const float4*)(lg+(size_t)4*(j+6));
    const float4 E7=*(const float4*)(lg+(size_t)4*(j+7));
    unsigned u0=*(const unsigned*)(v8+(size_t)s0*256+lane*4);
    unsigned u1=*(const unsigned*)(v8+(size_t)s1*256+lane*4);
    unsigned u2=*(const unsigned*)(v8+(size_t)s2*256+lane*4);
    unsigned u3=*(const unsigned*)(v8+(size_t)s3*256+lane*4);
    unsigned u4=*(const unsigned*)(v8+(size_t)s4*256+lane*4);
    unsigned u5=*(const unsigned*)(v8+(size_t)s5*256+lane*4);
    unsigned u6=*(const unsigned*)(v8+(size_t)s6*256+lane*4);
    unsigned u7=*(const unsigned*)(v8+(size_t)s7*256+lane*4);
    float p0,p1,p2,p3;
    f8x4(u0,p0,p1,p2,p3); a0+=E0.x*p0; a1+=E0.y*p1; a2+=E0.z*p2; a3+=E0.w*p3;
    f8x4(u1,p0,p1,p2,p3); a0+=E1.x*p0; a1+=E1.y*p1; a2+=E1.z*p2; a3+=E1.w*p3;
    f8x4(u2,p0,p1,p2,p3); a0+=E2.x*p0; a1+=E2.y*p1; a2+=E2.z*p2; a3+=E2.w*p3;
    f8x4(u3,p0,p1,p2,p3); a0+=E3.x*p0; a1+=E3.y*p1; a2+=E3.z*p2; a3+=E3.w*p3;
    f8x4(u4,p0,p1,p2,p3); a0+=E4.x*p0; a1+=E4.y*p1; a2+=E4.z*p2; a3+=E4.w*p3;
    f8x4(u5,p0,p1,p2,p3); a0+=E5.x*p0; a1+=E5.y*p1; a2+=E5.z*p2; a3+=E5.w*p3;
    f8x4(u6,p0,p1,p2,p3); a0+=E6.x*p0; a1+=E6.y*p1; a2+=E6.z*p2; a3+=E6.w*p3;
    f8x4(u7,p0,p1,p2,p3); a0+=E7.x*p0; a1+=E7.y*p1; a2+=E7.z*p2; a3+=E7.w*p3;
    z0+=((E0.x+E1.x)+(E2.x+E3.x))+((E4.x+E5.x)+(E6.x+E7.x));
    z1+=((E0.y+E1.y)+(E2.y+E3.y))+((E4.y+E5.y)+(E6.y+E7.y));
    z2+=((E0.z+E1.z)+(E2.z+E3.z))+((E4.z+E5.z)+(E6.z+E7.z));
    z3+=((E0.w+E1.w)+(E2.w+E3.w))+((E4.w+E5.w)+(E6.w+E7.w));
  }
  for(; j+3<r1; j+=4){
    int s0=sd[j].x, s1=sd[j+1].x, s2=sd[j+2].x, s3=sd[j+3].x;
    const float4 E0=*(const float4*)(lg+(size_t)4*j);
    const float4 E1=*(const float4*)(lg+(size_t)4*(j+1));
    const float4 E2=*(const float4*)(lg+(size_t)4*(j+2));
    const float4 E3=*(const float4*)(lg+(size_t)4*(j+3));
    unsigned u0=*(const unsigned*)(v8+(size_t)s0*256+lane*4);
    unsigned u1=*(const unsigned*)(v8+(size_t)s1*256+lane*4);
    unsigned u2=*(const unsigned*)(v8+(size_t)s2*256+lane*4);
    unsigned u3=*(const unsigned*)(v8+(size_t)s3*256+lane*4);
    float p0,p1,p2,p3;
    f8x4(u0,p0,p1,p2,p3); a0+=E0.x*p0; a1+=E0.y*p1; a2+=E0.z*p2; a3+=E0.w*p3;
    f8x4(u1,p0,p1,p2,p3); a0+=E1.x*p0; a1+=E1.y*p1; a2+=E1.z*p2; a3+=E1.w*p3;
    f8x4(u2,p0,p1,p2,p3); a0+=E2.x*p0; a1+=E2.y*p1; a2+=E2.z*p2; a3+=E2.w*p3;
    f8x4(u3,p0,p1,p2,p3); a0+=E3.x*p0; a1+=E3.y*p1; a2+=E3.z*p2; a3+=E3.w*p3;
    z0+=(E0.x+E1.x)+(E2.x+E3.x); z1+=(E0.y+E1.y)+(E2.y+E3.y);
    z2+=(E0.z+E1.z)+(E2.z+E3.z); z3+=(E0.w+E1.w)+(E2.w+E3.w);
  }
  for(; j<r1; j++){
    int s0=sd[j].x;
    const float4 E0=*(const float4*)(lg+(size_t)4*j);
    unsigned u0=*(const unsigned*)(v8+(size_t)s0*256+lane*4);
    float p0,p1,p2,p3; f8x4(u0,p0,p1,p2,p3);
    z0+=E0.x; z1+=E0.y; z2+=E0.z; z3+=E0.w;
    a0+=E0.x*p0; a1+=E0.y*p1; a2+=E0.z*p2; a3+=E0.w*p3;
  }
  float t=0.25f*(a0/(z0+1e-16f)+a1/(z1+1e-16f)+a2/(z2+1e-16f)+a3/(z3+1e-16f))+skip[(size_t)n*64+lane];
  x5b[(size_t)n*64+lane]=f2bf(fmaxf(t,0.f));
}

// EdgeConv: fp8 split P/Q gather -> LDS bf16 hidden -> MFMA GEMM2 -> parallel segmented max.
__global__ __launch_bounds__(256) void edgeconv3_kernel(
    const unsigned char* __restrict__ PQ8,
    const int2* __restrict__ sd,
    const unsigned short* __restrict__ W2t, const float* __restrict__ b2,
    unsigned* __restrict__ emax){
  __shared__ __align__(16) unsigned char smem[64*68*4];   // 17408 B union
  __shared__ int dstL[64];
  unsigned short (*Hs)[72]=(unsigned short(*)[72])smem;   // 9216 B live phase 1-2
  float (*As)[68]=(float(*)[68])smem;                     // 17408 B live phase 3-4
  const unsigned char* P8=PQ8;
  const unsigned char* Q8=PQ8+(size_t)N64;
  const int e0=blockIdx.x*64;
  const int tid=threadIdx.x;
  if(tid<64) dstL[tid]=sd[e0+tid].y;
  #pragma unroll
  for(int it=0;it<4;it++){
    int linear=it*1024+tid*4;
    int m=linear>>6, k=linear&63;
    int e=e0+m;
    int2 ep=sd[e];
    int dn=ep.y, sn=ep.x;
    unsigned pu=*(const unsigned*)(P8+(size_t)dn*64+k);
    unsigned qu=*(const unsigned*)(Q8+(size_t)sn*64+k);
    float p0,p1,p2,p3; f8x4(pu,p0,p1,p2,p3);
    float q0,q1,q2,q3; f8x4(qu,q0,q1,q2,q3);
    ushort4 hh;
    hh.x=f2bf(fmaxf(p0+q0,0.f));
    hh.y=f2bf(fmaxf(p1+q1,0.f));
    hh.z=f2bf(fmaxf(p2+q2,0.f));
    hh.w=f2bf(fmaxf(p3+q3,0.f));
    *(ushort4*)&Hs[m][k]=hh;
  }
  __syncthreads();
  const int w=tid>>6, l=tid&63, lo=l&15, quad=l>>4;
  const int colg=w*16+lo;
  ffrag acc[4];
  #pragma unroll
  for(int t=0;t<4;t++) acc[t]=(ffrag){0.f,0.f,0.f,0.f};
  #pragma unroll
  for(int kc=0;kc<64;kc+=32){
    bfrag b=*(const bfrag*)(W2t+(size_t)colg*64+kc+quad*8);
    #pragma unroll
    for(int t=0;t<4;t++){
      bfrag a=*(const bfrag*)(&Hs[t*16+lo][kc+quad*8]);
      acc[t]=__builtin_amdgcn_mfma_f32_16x16x32_bf16(a,b,acc[t],0,0,0);
    }
  }
  __syncthreads();                 // all Hs reads done before As overwrites the union
  float bv=b2[colg];
  #pragma unroll
  for(int t=0;t<4;t++)
    #pragma unroll
    for(int r=0;r<4;r++)
      As[t*16+quad*4+r][colg]=acc[t][r]+bv;
  __syncthreads();
  {
    const int c=tid&63, qtr=tid>>6, base=qtr*16;
    const int dFirst=dstL[base], dLast=dstL[base+15];
    int dprev=dFirst;
    float mx=As[base][c];
    #pragma unroll
    for(int i=1;i<16;i++){
      int dn=dstL[base+i];
      float v=As[base+i][c];
      if(dn!=dprev){
        unsigned* addr=&emax[(size_t)dprev*64+c];
        unsigned enc=fenc(mx);
        if(dprev!=dFirst && dprev!=dLast) *addr=enc;
        else atomicMax(addr,enc);
        dprev=dn; mx=v;
      }else mx=fmaxf(mx,v);
    }
    unsigned* addr=&emax[(size_t)dprev*64+c];
    unsigned enc=fenc(mx);
    if(dprev!=dFirst && dprev!=dLast) *addr=enc;
    else atomicMax(addr,enc);
  }
}

__global__ __launch_bounds__(256) void pool_kernel(const unsigned* __restrict__ emax, const int* __restrict__ batch,
                                                   float* __restrict__ pooled){
  const int NB=200;
  int base=blockIdx.x*NB;
  int lane=threadIdx.x&63;
  int wsub=threadIdx.x>>6;
  float acc=0.f; int curg=-1;
  for(int idx=wsub; idx<NB; idx+=4){
    int n=base+idx;
    if(n>=NN) break;
    int g=batch[n];
    if(g!=curg){
      if(curg>=0) atomicAdd(&pooled[curg*64+lane],acc);
      acc=0.f; curg=g;
    }
    unsigned u=emax[(size_t)n*64+lane];
    acc+=(u>=0x80000000u)? __uint_as_float(u&0x7fffffffu) : 0.f;
  }
  if(curg>=0) atomicAdd(&pooled[curg*64+lane],acc);
}

__global__ __launch_bounds__(256) void final_kernel(const float* __restrict__ pooled, const int* __restrict__ batch,
    const float* __restrict__ fc1W, const float* __restrict__ fc1b,
    const float* __restrict__ fc2W, const float* __restrict__ fc2b,
    float* __restrict__ out){
  __shared__ float gm[16][64];
  __shared__ float t1[16][64];
  __shared__ int cgs[17];
  int t=threadIdx.x;
  if(t<17){
    int lo=0, hi=NN;
    while(lo<hi){ int mid=(lo+hi)>>1; if(batch[mid]<t) lo=mid+1; else hi=mid; }
    cgs[t]=lo;
  }
  __syncthreads();
  for(int r=0;r<4;r++){
    int idx=r*256+t; int g=idx>>6, d=idx&63;
    float c=(float)(cgs[g+1]-cgs[g]);
    gm[g][d]=pooled[idx]/fmaxf(c,1.f);
  }
  __syncthreads();
  for(int r=0;r<4;r++){
    int idx=r*256+t; int g=idx>>6, d=idx&63;
    float a=fc1b[d];
    for(int k2=0;k2<64;k2++) a+=gm[g][k2]*fc1W[k2*64+d];
    t1[g][d]=fmaxf(a,0.f);
  }
  __syncthreads();
  for(int r=0;r<4;r++){
    int idx=r*256+t; int g=idx>>6, d=idx&63;
    float a=fc2b[d];
    for(int k2=0;k2<64;k2++) a+=t1[g][k2]*fc2W[k2*64+d];
    out[idx]=a;
  }
}

extern "C" void kernel_launch(void* const* d_in, const int* in_sizes, int n_in,
                              void* d_out, int out_size, void* d_ws, size_t ws_size,
                              hipStream_t stream){
  const float* x       =(const float*)d_in[0];
  const int*   ei      =(const int*)  d_in[1];
  const int*   src     =ei;
  const int*   dst     =ei+EE;
  const int*   batch   =(const int*)  d_in[2];
  const float* gat1_W  =(const float*)d_in[3];
  const float* gat1_as =(const float*)d_in[4];
  const float* gat1_ad =(const float*)d_in[5];
  const float* gat1_b  =(const float*)d_in[6];
  const float* gat2_W  =(const float*)d_in[7];
  const float* gat2_as =(const float*)d_in[8];
  const float* gat2_ad =(const float*)d_in[9];
  const float* gat2_b  =(const float*)d_in[10];
  const float* gin_W1  =(const float*)d_in[11];
  const float* gin_b1  =(const float*)d_in[12];
  const float* gin_W2  =(const float*)d_in[13];
  const float* gin_b2  =(const float*)d_in[14];
  const float* sage1_Wl=(const float*)d_in[15];
  const float* sage1_bl=(const float*)d_in[16];
  const float* sage1_Wr=(const float*)d_in[17];
  const float* sage2_Wl=(const float*)d_in[18];
  const float* sage2_bl=(const float*)d_in[19];
  const float* sage2_Wr=(const float*)d_in[20];
  const float* tr_Wq   =(const float*)d_in[21];
  const float* tr_bq   =(const float*)d_in[22];
  const float* tr_Wk   =(const float*)d_in[23];
  const float* tr_bk   =(const float*)d_in[24];
  const float* tr_Wv   =(const float*)d_in[25];
  const float* tr_bv   =(const float*)d_in[26];
  const float* tr_Ws   =(const float*)d_in[27];
  const float* tr_bs   =(const float*)d_in[28];
  const float* ec_W1   =(const float*)d_in[29];
  const float* ec_b1   =(const float*)d_in[30];
  const float* ec_W2   =(const float*)d_in[31];
  const float* ec_b2   =(const float*)d_in[32];
  const float* fc1_W   =(const float*)d_in[33];
  const float* fc1_b   =(const float*)d_in[34];
  const float* fc2_W   =(const float*)d_in[35];
  const float* fc2_b   =(const float*)d_in[36];

  // ---- workspace layout ----
  float* base=(float*)d_ws;
  size_t off=0;
  auto alloc=[&](size_t n){ float* p=base+off; off+=n; return p; };
  float* A_big =alloc((size_t)NN*256);
  float* nb0   =alloc(N64);
  float* nb1   =alloc(N64);
  float* nb2   =alloc(N64);
  float* nb3   =alloc(N64);
  float* nb4   =alloc(N64);
  float* nb5   =alloc(N64);                // emax
  float* logitE=alloc((size_t)EE*4);
  float* ls    =alloc(NN*4);
  float* ldb   =alloc(NN*4);
  float* invdeg=alloc(NN);
  float* pooled=alloc(GG*64);
  float* wbuf  =alloc(70000);
  float* bbuf  =alloc(640);
  int* ibase=(int*)(base+off);             // off is even -> 8B aligned
  int2* sd   =(int2*)ibase;                // [EE] packed (src,dst), 2*EE ints
  int* cnt   =ibase+2*EE;
  int* fillp =ibase+2*EE+NN;
  int* rowptr=ibase+2*EE+2*NN;
  int* bsum  =ibase+2*EE+3*NN+8;
  int* boff  =bsum+64;

  const int BT=256;
  const int NSB=cdiv(NN,1024);
  // ---- zero init ----
  zero_kernel<<<cdiv(2*NN,BT),BT,0,stream>>>((unsigned*)cnt,2*NN);
  zero_kernel<<<cdiv(GG*64,BT),BT,0,stream>>>((unsigned*)pooled,GG*64);
  zero_kernel<<<cdiv(N64,BT),BT,0,stream>>>((unsigned*)nb5,N64);
  // ---- CSR ----
  hist_kernel<<<cdiv(EE,BT),BT,0,stream>>>(dst,cnt);
  scan1_kernel<<<NSB,1024,0,stream>>>(cnt,rowptr,bsum);
  scan2_kernel<<<1,64,0,stream>>>(bsum,boff,rowptr,NSB);
  scan3_kernel<<<cdiv(NN,BT),BT,0,stream>>>(rowptr,boff,cnt,invdeg);
  fill_kernel<<<cdiv(EE,BT),BT,0,stream>>>(src,dst,rowptr,fillp,sd);

  const int GB=cdiv(NN,64);        // 782
  const int GW=cdiv(NN,4);         // 12500

  unsigned short* wt =(unsigned short*)wbuf;
  float* bqk=bbuf;
  float* bPQ=bbuf+512;
  unsigned char*  Abc  =(unsigned char*)A_big;                 // 51.2MB scratch
  unsigned char*  h8   =Abc;                                   // [N][64][4] fp8, 12.8MB
  unsigned char*  qk8  =Abc;                                   // [N][512]  fp8, 25.6MB
  unsigned char*  PQ8  =Abc;                                   // P [N][64] + Q [N][64], 6.4MB
  unsigned short* xb   =(unsigned short*)A_big+(size_t)NN*256; // bf16 x @25.6MB, 25.6MB
  unsigned char*  x2f8 =Abc+26000000;                          // 3.2MB (xb dead by then)
  unsigned char*  x3f8 =Abc+30000000;                          // 3.2MB
  unsigned char*  xsf8 =Abc+34000000;                          // 3.2MB
  unsigned short* xcatb=(unsigned short*)A_big;                // [N][128] bf16, 12.8MB
  unsigned short* x1b  =(unsigned short*)nb0;
  unsigned short* x2b  =(unsigned short*)nb1;
  unsigned short* tb   =(unsigned short*)nb2;
  unsigned short* hb3  =(unsigned short*)nb3;
  unsigned short* x3b  =(unsigned short*)nb1;
  unsigned short* xsb  =(unsigned short*)nb2;
  unsigned short* x4b  =(unsigned short*)nb0;
  unsigned char*  v8   =(unsigned char*)nb1;                   // [N][64][4] fp8
  unsigned short* x5b  =(unsigned short*)nb4;
  float* skipf=nb3;

  // ---- prep ----
  prep_kernel<<<cdiv(139904,BT),BT,0,stream>>>(gat1_W,gat2_W,gin_W1,gin_W2,
      sage1_Wl,sage1_Wr,sage2_Wl,sage2_Wr,tr_Wq,tr_Wk,tr_Wv,tr_Ws,ec_W1,ec_W2,
      tr_bq,tr_bk,ec_b1,wt,bqk,bPQ);
  cvtx_kernel<<<cdiv(NN*32,BT),BT,0,stream>>>(x,xb);

  // ---- GAT1 ----
  mgemm_kernel<128><<<dim3(GB,4),BT,0,stream>>>(xb,wt,nullptr,nullptr,nullptr,h8,256,0,1,
                                                gat1_as,gat1_ad,ls,ldb);
  gat_exp_kernel<<<cdiv(EE,BT),BT,0,stream>>>(sd,ls,ldb,logitE);
  gat1p_kernel<<<GW,BT,0,stream>>>(h8,rowptr,sd,logitE,ls,ldb,gat1_b,x1b,nullptr);
  // ---- GAT2 ----
  mgemm_kernel<64><<<dim3(GB,4),BT,0,stream>>>(x1b,wt+32768,nullptr,nullptr,nullptr,h8,256,0,1,
                                               gat2_as,gat2_ad,ls,ldb);
  gat_exp_kernel<<<cdiv(EE,BT),BT,0,stream>>>(sd,ls,ldb,logitE);
  gat1p_kernel<<<GW,BT,0,stream>>>(h8,rowptr,sd,logitE,ls,ldb,gat2_b,x2b,x2f8);
  // ---- GIN ----
  agg_kernel<<<GW,BT,0,stream>>>(x2b,x2f8,rowptr,sd,tb);
  mgemm_kernel<64><<<dim3(GB,1),BT,0,stream>>>(tb,wt+49152,gin_b1,nullptr,hb3,nullptr,64,1,0,
                                               nullptr,nullptr,nullptr,nullptr);
  mgemm_kernel<64><<<dim3(GB,1),BT,0,stream>>>(hb3,wt+53248,gin_b2,nullptr,x3b,x3f8,64,1,0,
                                               nullptr,nullptr,nullptr,nullptr);
  // ---- SAGE1 ----
  agg2_kernel<<<GW,BT,0,stream>>>(x3b,x3f8,rowptr,sd,invdeg,xcatb);
  mgemm_kernel<128><<<dim3(GB,1),BT,0,stream>>>(xcatb,wt+57344,sage1_bl,nullptr,xsb,xsf8,64,1,0,
                                                nullptr,nullptr,nullptr,nullptr);
  // ---- SAGE2 ----
  agg2_kernel<<<GW,BT,0,stream>>>(xsb,xsf8,rowptr,sd,invdeg,xcatb);
  mgemm_kernel<128><<<dim3(GB,1),BT,0,stream>>>(xcatb,wt+65536,sage2_bl,nullptr,x4b,nullptr,64,1,0,
                                                nullptr,nullptr,nullptr,nullptr);
  // ---- TransformerConv ----
  mgemm_kernel<64><<<dim3(GB,8),BT,0,stream>>>(x4b,wt+73728,bqk,nullptr,nullptr,qk8,512,0,0,
                                               nullptr,nullptr,nullptr,nullptr);   // q|k fp8
  tr_pass1_kernel<<<cdiv(EE,16),BT,0,stream>>>(sd,qk8,logitE);                     // exp(logits)
  mgemm_kernel<64><<<dim3(GB,4),BT,0,stream>>>(x4b,wt+106496,tr_bv,nullptr,nullptr,v8,256,0,1,
                                               nullptr,nullptr,nullptr,nullptr);   // v fp8
  mgemm_kernel<64><<<dim3(GB,1),BT,0,stream>>>(x4b,wt+122880,tr_bs,skipf,nullptr,nullptr,64,0,0,
                                               nullptr,nullptr,nullptr,nullptr);   // skip f32
  tr_pass2_kernel<<<GW,BT,0,stream>>>(rowptr,sd,logitE,v8,skipf,x5b);
  // ---- EdgeConv ----
  mgemm_kernel<64><<<dim3(GB,2),BT,0,stream>>>(x5b,wt+126976,bPQ,nullptr,nullptr,PQ8,64,0,2,
                                               nullptr,nullptr,nullptr,nullptr);
  edgeconv3_kernel<<<EE/64,BT,0,stream>>>(PQ8,sd,wt+135168,ec_b2,(unsigned*)nb5);
  // ---- pool + MLP ----
  pool_kernel<<<cdiv(NN,200),BT,0,stream>>>((unsigned*)nb5,batch,pooled);
  final_kernel<<<1,BT,0,stream>>>(pooled,batch,fc1_W,fc1_b,fc2_W,fc2_b,(float*)d_out);
}

// Round 9
// 726.390 us; speedup vs baseline: 1.0122x; 1.0122x over previous
//
#include <hip/hip_runtime.h>

#define NN 50000
#define EE 640000
#define GG 16
#define N64 (NN*64)

static inline int cdiv(int a,int b){return (a+b-1)/b;}

typedef __attribute__((ext_vector_type(8))) short bfrag;   // 8 bf16 (4 VGPR)
typedef __attribute__((ext_vector_type(4))) float ffrag;   // mfma accumulator
typedef __attribute__((ext_vector_type(2))) float f32x2;

__device__ __forceinline__ float lrelu(float x){ return x>0.f? x : 0.2f*x; }
__device__ __forceinline__ unsigned fenc(float f){
  unsigned u=__float_as_uint(f);
  return (u&0x80000000u)? ~u : (u|0x80000000u);
}
__device__ __forceinline__ float bf2f(unsigned short u){ return __uint_as_float(((unsigned)u)<<16); }
__device__ __forceinline__ unsigned short f2bf(float f){
  unsigned u=__float_as_uint(f);
  u += 0x7FFFu + ((u>>16)&1u);
  return (unsigned short)(u>>16);
}
// OCP e4m3 helpers (gfx950 hw cvt)
__device__ __forceinline__ unsigned char f2f8(float f){
  return (unsigned char)(__builtin_amdgcn_cvt_pk_fp8_f32(f,f,0,false)&0xff);
}
__device__ __forceinline__ void f8x4(unsigned u, float& e0,float& e1,float& e2,float& e3){
  f32x2 lo=__builtin_amdgcn_cvt_pk_f32_fp8((int)u,false);
  f32x2 hi=__builtin_amdgcn_cvt_pk_f32_fp8((int)u,true);
  e0=lo.x; e1=lo.y; e2=hi.x; e3=hi.y;
}
__device__ __forceinline__ float f8one(unsigned b){
  f32x2 lo=__builtin_amdgcn_cvt_pk_f32_fp8((int)b,false);
  return lo.x;
}
__device__ __forceinline__ float dot4f8(unsigned a, unsigned b){
  f32x2 al=__builtin_amdgcn_cvt_pk_f32_fp8((int)a,false);
  f32x2 ah=__builtin_amdgcn_cvt_pk_f32_fp8((int)a,true);
  f32x2 bl=__builtin_amdgcn_cvt_pk_f32_fp8((int)b,false);
  f32x2 bh=__builtin_amdgcn_cvt_pk_f32_fp8((int)b,true);
  return al.x*bl.x+al.y*bl.y+ah.x*bh.x+ah.y*bh.y;
}

__global__ void zero_kernel(unsigned* p, int n){
  int i=blockIdx.x*blockDim.x+threadIdx.x;
  if(i<n) p[i]=0u;
}

__global__ void hist_kernel(const int* __restrict__ dst, int* __restrict__ cnt){
  int e=blockIdx.x*blockDim.x+threadIdx.x;
  if(e<EE) atomicAdd(&cnt[dst[e]],1);
}

__global__ __launch_bounds__(1024) void scan1_kernel(const int* __restrict__ cnt,
    int* __restrict__ rowptr, int* __restrict__ bsum){
  __shared__ int wsum[16];
  int t=threadIdx.x, b=blockIdx.x;
  int i=b*1024+t;
  int v=(i<NN)?cnt[i]:0;
  int lane=t&63, w=t>>6;
  int inc=v;
  #pragma unroll
  for(int o=1;o<64;o<<=1){ int u=__shfl_up(inc,o,64); if(lane>=o) inc+=u; }
  if(lane==63) wsum[w]=inc;
  __syncthreads();
  if(t<16){
    int s=wsum[t];
    #pragma unroll
    for(int o=1;o<16;o<<=1){ int u=__shfl_up(s,o,16); if(t>=o) s+=u; }
    wsum[t]=s;
  }
  __syncthreads();
  int woff=(w>0)?wsum[w-1]:0;
  if(i<NN) rowptr[i]=woff+inc-v;
  if(t==1023) bsum[b]=wsum[15];
}

__global__ void scan2_kernel(const int* __restrict__ bsum, int* __restrict__ boff, int* __restrict__ rowptr, int nb){
  int t=threadIdx.x;
  int v=(t<nb)?bsum[t]:0;
  int inc=v;
  #pragma unroll
  for(int o=1;o<64;o<<=1){ int u=__shfl_up(inc,o,64); if(t>=o) inc+=u; }
  if(t<nb) boff[t]=inc-v;
  if(t==63) rowptr[NN]=inc;
}

// scan3: finalize rowptr, seed fillp=rowptr (fill uses atomicAdd directly), invdeg
__global__ void scan3_kernel(int* __restrict__ rowptr, const int* __restrict__ boff,
                             const int* __restrict__ cnt, int* __restrict__ fillp,
                             float* __restrict__ invdeg){
  int i=blockIdx.x*blockDim.x+threadIdx.x;
  if(i<NN){
    int rp=rowptr[i]+boff[i>>10];
    rowptr[i]=rp;
    fillp[i]=rp;
    invdeg[i]=1.f/fmaxf((float)cnt[i],1.f);
  }
}

// CSR fill: fillp pre-seeded with rowptr -> single atomic gives position; ONE int2
// scatter-store per edge (one dirty 64B line instead of two).
__global__ void fill_kernel(const int* __restrict__ src, const int* __restrict__ dst,
                            int* __restrict__ fillp, int2* __restrict__ sdtmp){
  int e=blockIdx.x*blockDim.x+threadIdx.x;
  if(e>=EE) return;
  int d=dst[e];
  int p=atomicAdd(&fillp[d],1);
  sdtmp[p]=make_int2(src[e],d);
}

// deinterleave sdtmp -> split srcS/dstS (sequential, keeps consumers on 4B streams)
__global__ void deint_kernel(const int2* __restrict__ sdtmp,
                             int* __restrict__ srcS, int* __restrict__ dstS){
  int i=blockIdx.x*blockDim.x+threadIdx.x;
  if(i>=EE) return;
  int2 v=sdtmp[i];
  srcS[i]=v.x; dstS[i]=v.y;
}

__global__ void cvtx_kernel(const float* __restrict__ x, unsigned short* __restrict__ xb){
  int i=blockIdx.x*blockDim.x+threadIdx.x;
  if(i>=NN*32) return;
  float4 v=*(const float4*)(x+(size_t)i*4);
  ushort4 o; o.x=f2bf(v.x); o.y=f2bf(v.y); o.z=f2bf(v.z); o.w=f2bf(v.w);
  *(ushort4*)(xb+(size_t)i*4)=o;
}

// weight prep: Wt[n][k]=W[k][n] bf16, all segments + bias packs
__global__ void prep_kernel(
    const float* __restrict__ g1W, const float* __restrict__ g2W,
    const float* __restrict__ giW1, const float* __restrict__ giW2,
    const float* __restrict__ s1Wl, const float* __restrict__ s1Wr,
    const float* __restrict__ s2Wl, const float* __restrict__ s2Wr,
    const float* __restrict__ Wq, const float* __restrict__ Wk,
    const float* __restrict__ Wv, const float* __restrict__ Ws,
    const float* __restrict__ ecW1, const float* __restrict__ ecW2,
    const float* __restrict__ bq, const float* __restrict__ bk, const float* __restrict__ eb1,
    unsigned short* __restrict__ wt, float* __restrict__ bqk, float* __restrict__ bPQ){
  int i=blockIdx.x*blockDim.x+threadIdx.x;
  if(i<32768){ int n=i>>7,k=i&127; wt[i]=f2bf(g1W[k*256+n]); return; } i-=32768;
  if(i<16384){ int n=i>>6,k=i&63; wt[32768+i]=f2bf(g2W[k*256+n]); return; } i-=16384;
  if(i<4096){ int n=i>>6,k=i&63; wt[49152+i]=f2bf(giW1[k*64+n]); return; } i-=4096;
  if(i<4096){ int n=i>>6,k=i&63; wt[53248+i]=f2bf(giW2[k*64+n]); return; } i-=4096;
  if(i<8192){ int n=i>>7,k=i&127; float v=(k<64)?s1Wl[k*64+n]:s1Wr[(k-64)*64+n];
              wt[57344+i]=f2bf(v); return; } i-=8192;
  if(i<8192){ int n=i>>7,k=i&127; float v=(k<64)?s2Wl[k*64+n]:s2Wr[(k-64)*64+n];
              wt[65536+i]=f2bf(v); return; } i-=8192;
  if(i<32768){ int n=i>>6,k=i&63; float v=(n<256)?Wq[k*256+n]:Wk[k*256+(n-256)];
               wt[73728+i]=f2bf(v); return; } i-=32768;
  if(i<16384){ int n=i>>6,k=i&63; wt[106496+i]=f2bf(Wv[k*256+n]); return; } i-=16384;
  if(i<4096){ int n=i>>6,k=i&63; wt[122880+i]=f2bf(Ws[k*64+n]); return; } i-=4096;
  if(i<8192){ int n=i>>6,k=i&63;
              float v=(n<64)?(ecW1[k*64+n]-ecW1[(64+k)*64+n]):ecW1[(64+k)*64+(n-64)];
              wt[126976+i]=f2bf(v); return; } i-=8192;
  if(i<4096){ int n=i>>6,k=i&63; wt[135168+i]=f2bf(ecW2[k*64+n]); return; } i-=4096;
  if(i<640){
    if(i<256) bqk[i]=bq[i];
    else if(i<512) bqk[i]=bk[i-256];
    else { int j=i-512; bPQ[j]=(j<64)?eb1[j]:0.f; }
  }
}

// bf16 MFMA GEMM with LDS A-staging: C[64x64 tile] = A[M,K]bf16 @ Wt[N,K]bf16^T (+bias)(relu)
template<int K>
__global__ __launch_bounds__(256) void mgemm_kernel(
    const unsigned short* __restrict__ A, const unsigned short* __restrict__ Wt,
    const float* __restrict__ bias,
    float* __restrict__ Cf, unsigned short* __restrict__ Cb, unsigned char* __restrict__ C8,
    int ldc, int relu_flag, int c8mode,
    const float* __restrict__ a_s, const float* __restrict__ a_d,
    float* __restrict__ lsO, float* __restrict__ ldO){
  __shared__ float lsP[2][4][64];
  __shared__ unsigned short As[64][K+8];
  const int m0=blockIdx.x*64;
  const int tid=threadIdx.x;
  #pragma unroll
  for(int it=0; it<K/32; ++it){
    int c = it*256 + tid;
    int row = c/(K/8), col8 = c%(K/8);
    int grow = m0+row; if(grow>=NN) grow=NN-1;
    *(bfrag*)&As[row][col8*8] = *(const bfrag*)(A+(size_t)grow*K+col8*8);
  }
  __syncthreads();
  const int w=tid>>6, l=tid&63, lo=l&15, quad=l>>4;
  const int colg=blockIdx.y*64 + w*16 + lo;
  const unsigned short* wrow=Wt+(size_t)colg*K+quad*8;
  ffrag acc[4];
  #pragma unroll
  for(int t=0;t<4;t++) acc[t]=(ffrag){0.f,0.f,0.f,0.f};
  #pragma unroll
  for(int kc=0;kc<K;kc+=32){
    bfrag b=*(const bfrag*)(wrow+kc);
    #pragma unroll
    for(int t=0;t<4;t++){
      bfrag a=*(const bfrag*)(&As[t*16+lo][kc+quad*8]);
      acc[t]=__builtin_amdgcn_mfma_f32_16x16x32_bf16(a,b,acc[t],0,0,0);
    }
  }
  float bv=bias?bias[colg]:0.f;
  float asv=0.f,adv=0.f;
  if(lsO){ asv=a_s[colg]; adv=a_d[colg]; }
  #pragma unroll
  for(int t=0;t<4;t++){
    #pragma unroll
    for(int r=0;r<4;r++){
      float v=acc[t][r]+bv;
      if(relu_flag) v=fmaxf(v,0.f);
      int row=m0+t*16+quad*4+r;
      if(row<NN){
        if(Cf) Cf[(size_t)row*ldc+colg]=v;
        if(Cb) Cb[(size_t)row*ldc+colg]=f2bf(v);
        if(C8){
          size_t idx;
          if(c8mode==1)      idx=(size_t)row*ldc + (((colg&63)<<2)|(colg>>6));
          else if(c8mode==2) idx=(size_t)((colg<64)?0:N64) + (size_t)row*64 + (colg&63);
          else               idx=(size_t)row*ldc + colg;
          C8[idx]=f2f8(v);
        }
      }
      if(lsO){
        float ps=v*asv, pd=v*adv;
        #pragma unroll
        for(int o=1;o<16;o<<=1){ ps+=__shfl_xor(ps,o,16); pd+=__shfl_xor(pd,o,16); }
        if(lo==0){ int lr=t*16+quad*4+r; lsP[0][w][lr]=ps; lsP[1][w][lr]=pd; }
      }
    }
  }
  if(lsO){
    __syncthreads();
    if(tid<64){
      int row=m0+tid;
      if(row<NN){
        lsO[(size_t)row*4+blockIdx.y]=lsP[0][0][tid]+lsP[0][1][tid]+lsP[0][2][tid]+lsP[0][3][tid];
        ldO[(size_t)row*4+blockIdx.y]=lsP[1][0][tid]+lsP[1][1][tid]+lsP[1][2][tid]+lsP[1][3][tid];
      }
    }
  }
}

// GAT edge exps: eE[j] = exp(lrelu(ls[src]+ld[dst])), one thread per edge (computed ONCE).
__global__ void gat_exp_kernel(const int* __restrict__ srcS, const int* __restrict__ dstS,
    const float* __restrict__ ls4, const float* __restrict__ ld4, float* __restrict__ eE){
  int j=blockIdx.x*blockDim.x+threadIdx.x;
  if(j>=EE) return;
  int s=srcS[j], d=dstS[j];
  const float4 a=*(const float4*)(ls4+(size_t)4*s);
  const float4 b=*(const float4*)(ld4+(size_t)4*d);
  *(float4*)(eE+(size_t)4*j)=make_float4(
    __expf(lrelu(a.x+b.x)),__expf(lrelu(a.y+b.y)),
    __expf(lrelu(a.z+b.z)),__expf(lrelu(a.w+b.w)));
}

// single-pass GAT, 2 waves/node edge-split, precomputed edge exps, fp8 h gather (R6/R3 form).
__global__ __launch_bounds__(256) void gat1p_kernel(const unsigned char* __restrict__ h8,
    const int* __restrict__ rowptr, const int* __restrict__ srcS,
    const float* __restrict__ eE,
    const float* __restrict__ ls4, const float* __restrict__ ld4,
    const float* __restrict__ bias, unsigned short* __restrict__ outb,
    unsigned char* __restrict__ out8){
  __shared__ float cz[4][4];
  __shared__ float ca[4][4][64];
  int w=threadIdx.x>>6, lane=threadIdx.x&63;
  int n=blockIdx.x*2+(w>>1);
  int half=w&1;
  float z0=0.f,z1=0.f,z2=0.f,z3=0.f;
  float a0=0.f,a1=0.f,a2=0.f,a3=0.f;
  if(n<NN){
    int r0=rowptr[n], r1=rowptr[n+1];
    int mid=(r0+r1)>>1;
    if(half==0){
      const float4 ldv=*(const float4*)(ld4+(size_t)4*n);
      const float4 lsv=*(const float4*)(ls4+(size_t)4*n);
      z0=__expf(lrelu(lsv.x+ldv.x)); z1=__expf(lrelu(lsv.y+ldv.y));
      z2=__expf(lrelu(lsv.z+ldv.z)); z3=__expf(lrelu(lsv.w+ldv.w));
      float h0,h1,h2,h3;
      f8x4(*(const unsigned*)(h8+(size_t)n*256+lane*4),h0,h1,h2,h3);
      a0=z0*h0; a1=z1*h1; a2=z2*h2; a3=z3*h3;
    }
    int j = half? mid : r0;
    int je= half? r1  : mid;
    for(; j+3<je; j+=4){
      int s0=srcS[j], s1=srcS[j+1], s2=srcS[j+2], s3=srcS[j+3];
      const float4 E0=*(const float4*)(eE+(size_t)4*j);
      const float4 E1=*(const float4*)(eE+(size_t)4*(j+1));
      const float4 E2=*(const float4*)(eE+(size_t)4*(j+2));
      const float4 E3=*(const float4*)(eE+(size_t)4*(j+3));
      unsigned u0=*(const unsigned*)(h8+(size_t)s0*256+lane*4);
      unsigned u1=*(const unsigned*)(h8+(size_t)s1*256+lane*4);
      unsigned u2=*(const unsigned*)(h8+(size_t)s2*256+lane*4);
      unsigned u3=*(const unsigned*)(h8+(size_t)s3*256+lane*4);
      float h00,h01,h02,h03; f8x4(u0,h00,h01,h02,h03);
      float h10,h11,h12,h13; f8x4(u1,h10,h11,h12,h13);
      float h20,h21,h22,h23; f8x4(u2,h20,h21,h22,h23);
      float h30,h31,h32,h33; f8x4(u3,h30,h31,h32,h33);
      z0+=(E0.x+E1.x)+(E2.x+E3.x); z1+=(E0.y+E1.y)+(E2.y+E3.y);
      z2+=(E0.z+E1.z)+(E2.z+E3.z); z3+=(E0.w+E1.w)+(E2.w+E3.w);
      a0+=(E0.x*h00+E1.x*h10)+(E2.x*h20+E3.x*h30);
      a1+=(E0.y*h01+E1.y*h11)+(E2.y*h21+E3.y*h31);
      a2+=(E0.z*h02+E1.z*h12)+(E2.z*h22+E3.z*h32);
      a3+=(E0.w*h03+E1.w*h13)+(E2.w*h23+E3.w*h33);
    }
    for(; j<je; j++){
      int s0=srcS[j];
      const float4 E0=*(const float4*)(eE+(size_t)4*j);
      unsigned u0=*(const unsigned*)(h8+(size_t)s0*256+lane*4);
      float h00,h01,h02,h03; f8x4(u0,h00,h01,h02,h03);
      z0+=E0.x; z1+=E0.y; z2+=E0.z; z3+=E0.w;
      a0+=E0.x*h00; a1+=E0.y*h01; a2+=E0.z*h02; a3+=E0.w*h03;
    }
  }
  if(lane==0){ cz[w][0]=z0; cz[w][1]=z1; cz[w][2]=z2; cz[w][3]=z3; }
  ca[w][0][lane]=a0; ca[w][1][lane]=a1; ca[w][2][lane]=a2; ca[w][3][lane]=a3;
  __syncthreads();
  if(threadIdx.x<128){
    int ni=threadIdx.x>>6, l=threadIdx.x&63;
    int n2=blockIdx.x*2+ni;
    if(n2<NN){
      int w0=ni*2, w1=w0+1;
      float Z0=cz[w0][0]+cz[w1][0], Z1=cz[w0][1]+cz[w1][1];
      float Z2=cz[w0][2]+cz[w1][2], Z3=cz[w0][3]+cz[w1][3];
      float A0=ca[w0][0][l]+ca[w1][0][l], A1=ca[w0][1][l]+ca[w1][1][l];
      float A2=ca[w0][2][l]+ca[w1][2][l], A3=ca[w0][3][l]+ca[w1][3][l];
      float r=0.25f*(A0/(Z0+1e-16f)+A1/(Z1+1e-16f)+A2/(Z2+1e-16f)+A3/(Z3+1e-16f))+bias[l];
      float rr=fmaxf(r,0.f);
      outb[(size_t)n2*64+l]=f2bf(rr);
      if(out8) out8[(size_t)n2*64+l]=f2f8(rr);
    }
  }
}

// GIN: self(bf16) + sum of neighbors (fp8 L2-resident gather), unroll 4
__global__ __launch_bounds__(256) void agg_kernel(const unsigned short* __restrict__ xin,
    const unsigned char* __restrict__ xin8,
    const int* __restrict__ rowptr, const int* __restrict__ srcS,
    unsigned short* __restrict__ out){
  int n=blockIdx.x*4+(threadIdx.x>>6);
  int lane=threadIdx.x&63;
  if(n>=NN) return;
  int r0=rowptr[n], r1=rowptr[n+1];
  float acc=bf2f(xin[(size_t)n*64+lane]);
  int j=r0;
  for(; j+3<r1; j+=4){
    int s0=srcS[j], s1=srcS[j+1], s2=srcS[j+2], s3=srcS[j+3];
    unsigned b0=xin8[(size_t)s0*64+lane];
    unsigned b1=xin8[(size_t)s1*64+lane];
    unsigned b2=xin8[(size_t)s2*64+lane];
    unsigned b3=xin8[(size_t)s3*64+lane];
    acc+=(f8one(b0)+f8one(b1))+(f8one(b2)+f8one(b3));
  }
  for(; j<r1; j++) acc+=f8one(xin8[(size_t)srcS[j]*64+lane]);
  out[(size_t)n*64+lane]=f2bf(acc);
}

// SAGE staging: out128b[n]=[mean_neigh(fp8 gather), self(bf16)] bf16, unroll 4
__global__ __launch_bounds__(256) void agg2_kernel(const unsigned short* __restrict__ xin,
    const unsigned char* __restrict__ xin8,
    const int* __restrict__ rowptr, const int* __restrict__ srcS,
    const float* __restrict__ invdeg, unsigned short* __restrict__ out128b){
  int n=blockIdx.x*4+(threadIdx.x>>6);
  int lane=threadIdx.x&63;
  if(n>=NN) return;
  int r0=rowptr[n], r1=rowptr[n+1];
  float acc=0.f;
  int j=r0;
  for(; j+3<r1; j+=4){
    int s0=srcS[j], s1=srcS[j+1], s2=srcS[j+2], s3=srcS[j+3];
    unsigned b0=xin8[(size_t)s0*64+lane];
    unsigned b1=xin8[(size_t)s1*64+lane];
    unsigned b2=xin8[(size_t)s2*64+lane];
    unsigned b3=xin8[(size_t)s3*64+lane];
    acc+=(f8one(b0)+f8one(b1))+(f8one(b2)+f8one(b3));
  }
  for(; j<r1; j++) acc+=f8one(xin8[(size_t)srcS[j]*64+lane]);
  out128b[(size_t)n*128+lane]=f2bf(acc*invdeg[n]);
  out128b[(size_t)n*128+64+lane]=xin[(size_t)n*64+lane];
}

// TR pass1 (edge-parallel SDDMM): qk8 [N,512] fp8 (q|k head-major); stores EXP of logits.
__global__ __launch_bounds__(256) void tr_pass1_kernel(const int* __restrict__ srcS, const int* __restrict__ dstS,
    const unsigned char* __restrict__ qk8, float* __restrict__ lg){
  int e=blockIdx.x*16+(threadIdx.x>>4);
  int t=threadIdx.x&15;
  if(e>=EE) return;
  int s=srcS[e], d=dstS[e];
  const unsigned char* qd=qk8+(size_t)d*512+t*4;
  const unsigned char* ks=qk8+(size_t)s*512+256+t*4;
  unsigned ku0=*(const unsigned*)(ks);
  unsigned ku1=*(const unsigned*)(ks+64);
  unsigned ku2=*(const unsigned*)(ks+128);
  unsigned ku3=*(const unsigned*)(ks+192);
  unsigned qu0=*(const unsigned*)(qd);
  unsigned qu1=*(const unsigned*)(qd+64);
  unsigned qu2=*(const unsigned*)(qd+128);
  unsigned qu3=*(const unsigned*)(qd+192);
  float v0=dot4f8(ku0,qu0);
  float v1=dot4f8(ku1,qu1);
  float v2=dot4f8(ku2,qu2);
  float v3=dot4f8(ku3,qu3);
  #pragma unroll
  for(int o=1;o<16;o<<=1){
    v0+=__shfl_xor(v0,o,16); v1+=__shfl_xor(v1,o,16);
    v2+=__shfl_xor(v2,o,16); v3+=__shfl_xor(v3,o,16);
  }
  if(t==0)
    *(float4*)(lg+(size_t)4*e)=make_float4(__expf(v0*0.125f),__expf(v1*0.125f),
                                           __expf(v2*0.125f),__expf(v3*0.125f));
}

// TR pass2: 2 waves/node edge-split, precomputed exps + fp8 v-gather + skip + relu (R6/R3 form)
__global__ __launch_bounds__(256) void tr_pass2_kernel(const int* __restrict__ rowptr, const int* __restrict__ srcS,
    const float* __restrict__ lg,
    const unsigned char* __restrict__ v8, const float* __restrict__ skip, unsigned short* __restrict__ x5b){
  __shared__ float cz[4][4];
  __shared__ float ca[4][4][64];
  int w=threadIdx.x>>6, lane=threadIdx.x&63;
  int n=blockIdx.x*2+(w>>1);
  int half=w&1;
  float z0=0.f,z1=0.f,z2=0.f,z3=0.f;
  float a0=0.f,a1=0.f,a2=0.f,a3=0.f;
  if(n<NN){
    int r0=rowptr[n], r1=rowptr[n+1];
    int mid=(r0+r1)>>1;
    int j = half? mid : r0;
    int je= half? r1  : mid;
    for(; j+3<je; j+=4){
      int s0=srcS[j], s1=srcS[j+1], s2=srcS[j+2], s3=srcS[j+3];
      const float4 E0=*(const float4*)(lg+(size_t)4*j);
      const float4 E1=*(const float4*)(lg+(size_t)4*(j+1));
      const float4 E2=*(const float4*)(lg+(size_t)4*(j+2));
      const float4 E3=*(const float4*)(lg+(size_t)4*(j+3));
      unsigned u0=*(const unsigned*)(v8+(size_t)s0*256+lane*4);
      unsigned u1=*(const unsigned*)(v8+(size_t)s1*256+lane*4);
      unsigned u2=*(const unsigned*)(v8+(size_t)s2*256+lane*4);
      unsigned u3=*(const unsigned*)(v8+(size_t)s3*256+lane*4);
      float h00,h01,h02,h03; f8x4(u0,h00,h01,h02,h03);
      float h10,h11,h12,h13; f8x4(u1,h10,h11,h12,h13);
      float h20,h21,h22,h23; f8x4(u2,h20,h21,h22,h23);
      float h30,h31,h32,h33; f8x4(u3,h30,h31,h32,h33);
      z0+=(E0.x+E1.x)+(E2.x+E3.x); z1+=(E0.y+E1.y)+(E2.y+E3.y);
      z2+=(E0.z+E1.z)+(E2.z+E3.z); z3+=(E0.w+E1.w)+(E2.w+E3.w);
      a0+=(E0.x*h00+E1.x*h10)+(E2.x*h20+E3.x*h30);
      a1+=(E0.y*h01+E1.y*h11)+(E2.y*h21+E3.y*h31);
      a2+=(E0.z*h02+E1.z*h12)+(E2.z*h22+E3.z*h32);
      a3+=(E0.w*h03+E1.w*h13)+(E2.w*h23+E3.w*h33);
    }
    for(; j<je; j++){
      int s0=srcS[j];
      const float4 E0=*(const float4*)(lg+(size_t)4*j);
      unsigned u0=*(const unsigned*)(v8+(size_t)s0*256+lane*4);
      float h00,h01,h02,h03; f8x4(u0,h00,h01,h02,h03);
      z0+=E0.x; z1+=E0.y; z2+=E0.z; z3+=E0.w;
      a0+=E0.x*h00; a1+=E0.y*h01; a2+=E0.z*h02; a3+=E0.w*h03;
    }
  }
  if(lane==0){ cz[w][0]=z0; cz[w][1]=z1; cz[w][2]=z2; cz[w][3]=z3; }
  ca[w][0][lane]=a0; ca[w][1][lane]=a1; ca[w][2][lane]=a2; ca[w][3][lane]=a3;
  __syncthreads();
  if(threadIdx.x<128){
    int ni=threadIdx.x>>6, l=threadIdx.x&63;
    int n2=blockIdx.x*2+ni;
    if(n2<NN){
      int w0=ni*2, w1=w0+1;
      float Z0=cz[w0][0]+cz[w1][0], Z1=cz[w0][1]+cz[w1][1];
      float Z2=cz[w0][2]+cz[w1][2], Z3=cz[w0][3]+cz[w1][3];
      float A0=ca[w0][0][l]+ca[w1][0][l], A1=ca[w0][1][l]+ca[w1][1][l];
      float A2=ca[w0][2][l]+ca[w1][2][l], A3=ca[w0][3][l]+ca[w1][3][l];
      float t=0.25f*(A0/(Z0+1e-16f)+A1/(Z1+1e-16f)+A2/(Z2+1e-16f)+A3/(Z3+1e-16f))+skip[(size_t)n2*64+l];
      x5b[(size_t)n2*64+l]=f2bf(fmaxf(t,0.f));
    }
  }
}

// EdgeConv: fp8 split P/Q gather -> LDS bf16 hidden -> MFMA GEMM2 -> parallel segmented max.
__global__ __launch_bounds__(256) void edgeconv3_kernel(
    const unsigned char* __restrict__ PQ8,
    const int* __restrict__ srcS, const int* __restrict__ dstS,
    const unsigned short* __restrict__ W2t, const float* __restrict__ b2,
    unsigned* __restrict__ emax){
  __shared__ __align__(16) unsigned char smem[64*68*4];   // 17408 B union
  __shared__ int dstL[64];
  unsigned short (*Hs)[72]=(unsigned short(*)[72])smem;   // 9216 B live phase 1-2
  float (*As)[68]=(float(*)[68])smem;                     // 17408 B live phase 3-4
  const unsigned char* P8=PQ8;
  const unsigned char* Q8=PQ8+(size_t)N64;
  const int e0=blockIdx.x*64;
  const int tid=threadIdx.x;
  if(tid<64) dstL[tid]=dstS[e0+tid];
  #pragma unroll
  for(int it=0;it<4;it++){
    int linear=it*1024+tid*4;
    int m=linear>>6, k=linear&63;
    int e=e0+m;
    int dn=dstS[e], sn=srcS[e];
    unsigned pu=*(const unsigned*)(P8+(size_t)dn*64+k);
    unsigned qu=*(const unsigned*)(Q8+(size_t)sn*64+k);
    float p0,p1,p2,p3; f8x4(pu,p0,p1,p2,p3);
    float q0,q1,q2,q3; f8x4(qu,q0,q1,q2,q3);
    ushort4 hh;
    hh.x=f2bf(fmaxf(p0+q0,0.f));
    hh.y=f2bf(fmaxf(p1+q1,0.f));
    hh.z=f2bf(fmaxf(p2+q2,0.f));
    hh.w=f2bf(fmaxf(p3+q3,0.f));
    *(ushort4*)&Hs[m][k]=hh;
  }
  __syncthreads();
  const int w=tid>>6, l=tid&63, lo=l&15, quad=l>>4;
  const int colg=w*16+lo;
  ffrag acc[4];
  #pragma unroll
  for(int t=0;t<4;t++) acc[t]=(ffrag){0.f,0.f,0.f,0.f};
  #pragma unroll
  for(int kc=0;kc<64;kc+=32){
    bfrag b=*(const bfrag*)(W2t+(size_t)colg*64+kc+quad*8);
    #pragma unroll
    for(int t=0;t<4;t++){
      bfrag a=*(const bfrag*)(&Hs[t*16+lo][kc+quad*8]);
      acc[t]=__builtin_amdgcn_mfma_f32_16x16x32_bf16(a,b,acc[t],0,0,0);
    }
  }
  __syncthreads();                 // all Hs reads done before As overwrites the union
  float bv=b2[colg];
  #pragma unroll
  for(int t=0;t<4;t++)
    #pragma unroll
    for(int r=0;r<4;r++)
      As[t*16+quad*4+r][colg]=acc[t][r]+bv;
  __syncthreads();
  {
    const int c=tid&63, qtr=tid>>6, base=qtr*16;
    const int dFirst=dstL[base], dLast=dstL[base+15];
    int dprev=dFirst;
    float mx=As[base][c];
    #pragma unroll
    for(int i=1;i<16;i++){
      int dn=dstL[base+i];
      float v=As[base+i][c];
      if(dn!=dprev){
        unsigned* addr=&emax[(size_t)dprev*64+c];
        unsigned enc=fenc(mx);
        if(dprev!=dFirst && dprev!=dLast) *addr=enc;
        else atomicMax(addr,enc);
        dprev=dn; mx=v;
      }else mx=fmaxf(mx,v);
    }
    unsigned* addr=&emax[(size_t)dprev*64+c];
    unsigned enc=fenc(mx);
    if(dprev!=dFirst && dprev!=dLast) *addr=enc;
    else atomicMax(addr,enc);
  }
}

__global__ __launch_bounds__(256) void pool_kernel(const unsigned* __restrict__ emax, const int* __restrict__ batch,
                                                   float* __restrict__ pooled){
  const int NB=200;
  int base=blockIdx.x*NB;
  int lane=threadIdx.x&63;
  int wsub=threadIdx.x>>6;
  float acc=0.f; int curg=-1;
  for(int idx=wsub; idx<NB; idx+=4){
    int n=base+idx;
    if(n>=NN) break;
    int g=batch[n];
    if(g!=curg){
      if(curg>=0) atomicAdd(&pooled[curg*64+lane],acc);
      acc=0.f; curg=g;
    }
    unsigned u=emax[(size_t)n*64+lane];
    acc+=(u>=0x80000000u)? __uint_as_float(u&0x7fffffffu) : 0.f;
  }
  if(curg>=0) atomicAdd(&pooled[curg*64+lane],acc);
}

__global__ __launch_bounds__(256) void final_kernel(const float* __restrict__ pooled, const int* __restrict__ batch,
    const float* __restrict__ fc1W, const float* __restrict__ fc1b,
    const float* __restrict__ fc2W, const float* __restrict__ fc2b,
    float* __restrict__ out){
  __shared__ float gm[16][64];
  __shared__ float t1[16][64];
  __shared__ int cgs[17];
  int t=threadIdx.x;
  if(t<17){
    int lo=0, hi=NN;
    while(lo<hi){ int mid=(lo+hi)>>1; if(batch[mid]<t) lo=mid+1; else hi=mid; }
    cgs[t]=lo;
  }
  __syncthreads();
  for(int r=0;r<4;r++){
    int idx=r*256+t; int g=idx>>6, d=idx&63;
    float c=(float)(cgs[g+1]-cgs[g]);
    gm[g][d]=pooled[idx]/fmaxf(c,1.f);
  }
  __syncthreads();
  for(int r=0;r<4;r++){
    int idx=r*256+t; int g=idx>>6, d=idx&63;
    float a=fc1b[d];
    for(int k2=0;k2<64;k2++) a+=gm[g][k2]*fc1W[k2*64+d];
    t1[g][d]=fmaxf(a,0.f);
  }
  __syncthreads();
  for(int r=0;r<4;r++){
    int idx=r*256+t; int g=idx>>6, d=idx&63;
    float a=fc2b[d];
    for(int k2=0;k2<64;k2++) a+=t1[g][k2]*fc2W[k2*64+d];
    out[idx]=a;
  }
}

extern "C" void kernel_launch(void* const* d_in, const int* in_sizes, int n_in,
                              void* d_out, int out_size, void* d_ws, size_t ws_size,
                              hipStream_t stream){
  const float* x       =(const float*)d_in[0];
  const int*   ei      =(const int*)  d_in[1];
  const int*   src     =ei;
  const int*   dst     =ei+EE;
  const int*   batch   =(const int*)  d_in[2];
  const float* gat1_W  =(const float*)d_in[3];
  const float* gat1_as =(const float*)d_in[4];
  const float* gat1_ad =(const float*)d_in[5];
  const float* gat1_b  =(const float*)d_in[6];
  const float* gat2_W  =(const float*)d_in[7];
  const float* gat2_as =(const float*)d_in[8];
  const float* gat2_ad =(const float*)d_in[9];
  const float* gat2_b  =(const float*)d_in[10];
  const float* gin_W1  =(const float*)d_in[11];
  const float* gin_b1  =(const float*)d_in[12];
  const float* gin_W2  =(const float*)d_in[13];
  const float* gin_b2  =(const float*)d_in[14];
  const float* sage1_Wl=(const float*)d_in[15];
  const float* sage1_bl=(const float*)d_in[16];
  const float* sage1_Wr=(const float*)d_in[17];
  const float* sage2_Wl=(const float*)d_in[18];
  const float* sage2_bl=(const float*)d_in[19];
  const float* sage2_Wr=(const float*)d_in[20];
  const float* tr_Wq   =(const float*)d_in[21];
  const float* tr_bq   =(const float*)d_in[22];
  const float* tr_Wk   =(const float*)d_in[23];
  const float* tr_bk   =(const float*)d_in[24];
  const float* tr_Wv   =(const float*)d_in[25];
  const float* tr_bv   =(const float*)d_in[26];
  const float* tr_Ws   =(const float*)d_in[27];
  const float* tr_bs   =(const float*)d_in[28];
  const float* ec_W1   =(const float*)d_in[29];
  const float* ec_b1   =(const float*)d_in[30];
  const float* ec_W2   =(const float*)d_in[31];
  const float* ec_b2   =(const float*)d_in[32];
  const float* fc1_W   =(const float*)d_in[33];
  const float* fc1_b   =(const float*)d_in[34];
  const float* fc2_W   =(const float*)d_in[35];
  const float* fc2_b   =(const float*)d_in[36];

  // ---- workspace layout ----
  float* base=(float*)d_ws;
  size_t off=0;
  auto alloc=[&](size_t n){ float* p=base+off; off+=n; return p; };
  float* A_big =alloc((size_t)NN*256);
  float* nb0   =alloc(N64);
  float* nb1   =alloc(N64);
  float* nb2   =alloc(N64);
  float* nb3   =alloc(N64);
  float* nb4   =alloc(N64);
  float* nb5   =alloc(N64);                // emax
  float* logitE=alloc((size_t)EE*4);
  float* ls    =alloc(NN*4);
  float* ldb   =alloc(NN*4);
  float* invdeg=alloc(NN);
  float* pooled=alloc(GG*64);
  float* wbuf  =alloc(70000);
  float* bbuf  =alloc(640);
  int* ibase=(int*)(base+off);             // 8B-aligned (all allocs even)
  int2* sdtmp=(int2*)ibase;                // [EE] interleaved scratch (2*EE ints)
  int* srcS  =ibase+2*EE;
  int* dstS  =ibase+3*EE;
  int* cnt   =ibase+4*EE;
  int* fillp =ibase+4*EE+NN;
  int* rowptr=ibase+4*EE+2*NN;
  int* bsum  =ibase+4*EE+3*NN+8;
  int* boff  =bsum+64;

  const int BT=256;
  const int NSB=cdiv(NN,1024);
  // ---- zero init ----
  zero_kernel<<<cdiv(NN,BT),BT,0,stream>>>((unsigned*)cnt,NN);
  zero_kernel<<<cdiv(GG*64,BT),BT,0,stream>>>((unsigned*)pooled,GG*64);
  zero_kernel<<<cdiv(N64,BT),BT,0,stream>>>((unsigned*)nb5,N64);
  // ---- CSR ----
  hist_kernel<<<cdiv(EE,BT),BT,0,stream>>>(dst,cnt);
  scan1_kernel<<<NSB,1024,0,stream>>>(cnt,rowptr,bsum);
  scan2_kernel<<<1,64,0,stream>>>(bsum,boff,rowptr,NSB);
  scan3_kernel<<<cdiv(NN,BT),BT,0,stream>>>(rowptr,boff,cnt,fillp,invdeg);
  fill_kernel<<<cdiv(EE,BT),BT,0,stream>>>(src,dst,fillp,sdtmp);
  deint_kernel<<<cdiv(EE,BT),BT,0,stream>>>(sdtmp,srcS,dstS);

  const int GB=cdiv(NN,64);        // 782
  const int GW=cdiv(NN,4);         // 12500
  const int GW2=cdiv(NN,2);        // 25000

  unsigned short* wt =(unsigned short*)wbuf;
  float* bqk=bbuf;
  float* bPQ=bbuf+512;
  unsigned char*  Abc  =(unsigned char*)A_big;                 // 51.2MB scratch
  unsigned char*  h8   =Abc;                                   // [N][64][4] fp8, 12.8MB
  unsigned char*  qk8  =Abc;                                   // [N][512]  fp8, 25.6MB
  unsigned char*  PQ8  =Abc;                                   // P [N][64] + Q [N][64], 6.4MB
  unsigned short* xb   =(unsigned short*)A_big+(size_t)NN*256; // bf16 x @25.6MB, 25.6MB
  unsigned char*  x2f8 =Abc+26000000;                          // 3.2MB (xb dead by then)
  unsigned char*  x3f8 =Abc+30000000;                          // 3.2MB
  unsigned char*  xsf8 =Abc+34000000;                          // 3.2MB
  unsigned short* xcatb=(unsigned short*)A_big;                // [N][128] bf16, 12.8MB
  unsigned short* x1b  =(unsigned short*)nb0;
  unsigned short* x2b  =(unsigned short*)nb1;
  unsigned short* tb   =(unsigned short*)nb2;
  unsigned short* hb3  =(unsigned short*)nb3;
  unsigned short* x3b  =(unsigned short*)nb1;
  unsigned short* xsb  =(unsigned short*)nb2;
  unsigned short* x4b  =(unsigned short*)nb0;
  unsigned char*  v8   =(unsigned char*)nb1;                   // [N][64][4] fp8
  unsigned short* x5b  =(unsigned short*)nb4;
  float* skipf=nb3;

  // ---- prep ----
  prep_kernel<<<cdiv(139904,BT),BT,0,stream>>>(gat1_W,gat2_W,gin_W1,gin_W2,
      sage1_Wl,sage1_Wr,sage2_Wl,sage2_Wr,tr_Wq,tr_Wk,tr_Wv,tr_Ws,ec_W1,ec_W2,
      tr_bq,tr_bk,ec_b1,wt,bqk,bPQ);
  cvtx_kernel<<<cdiv(NN*32,BT),BT,0,stream>>>(x,xb);

  // ---- GAT1 ----
  mgemm_kernel<128><<<dim3(GB,4),BT,0,stream>>>(xb,wt,nullptr,nullptr,nullptr,h8,256,0,1,
                                                gat1_as,gat1_ad,ls,ldb);
  gat_exp_kernel<<<cdiv(EE,BT),BT,0,stream>>>(srcS,dstS,ls,ldb,logitE);
  gat1p_kernel<<<GW2,BT,0,stream>>>(h8,rowptr,srcS,logitE,ls,ldb,gat1_b,x1b,nullptr);
  // ---- GAT2 ----
  mgemm_kernel<64><<<dim3(GB,4),BT,0,stream>>>(x1b,wt+32768,nullptr,nullptr,nullptr,h8,256,0,1,
                                               gat2_as,gat2_ad,ls,ldb);
  gat_exp_kernel<<<cdiv(EE,BT),BT,0,stream>>>(srcS,dstS,ls,ldb,logitE);
  gat1p_kernel<<<GW2,BT,0,stream>>>(h8,rowptr,srcS,logitE,ls,ldb,gat2_b,x2b,x2f8);
  // ---- GIN ----
  agg_kernel<<<GW,BT,0,stream>>>(x2b,x2f8,rowptr,srcS,tb);
  mgemm_kernel<64><<<dim3(GB,1),BT,0,stream>>>(tb,wt+49152,gin_b1,nullptr,hb3,nullptr,64,1,0,
                                               nullptr,nullptr,nullptr,nullptr);
  mgemm_kernel<64><<<dim3(GB,1),BT,0,stream>>>(hb3,wt+53248,gin_b2,nullptr,x3b,x3f8,64,1,0,
                                               nullptr,nullptr,nullptr,nullptr);
  // ---- SAGE1 ----
  agg2_kernel<<<GW,BT,0,stream>>>(x3b,x3f8,rowptr,srcS,invdeg,xcatb);
  mgemm_kernel<128><<<dim3(GB,1),BT,0,stream>>>(xcatb,wt+57344,sage1_bl,nullptr,xsb,xsf8,64,1,0,
                                                nullptr,nullptr,nullptr,nullptr);
  // ---- SAGE2 ----
  agg2_kernel<<<GW,BT,0,stream>>>(xsb,xsf8,rowptr,srcS,invdeg,xcatb);
  mgemm_kernel<128><<<dim3(GB,1),BT,0,stream>>>(xcatb,wt+65536,sage2_bl,nullptr,x4b,nullptr,64,1,0,
                                                nullptr,nullptr,nullptr,nullptr);
  // ---- TransformerConv ----
  mgemm_kernel<64><<<dim3(GB,8),BT,0,stream>>>(x4b,wt+73728,bqk,nullptr,nullptr,qk8,512,0,0,
                                               nullptr,nullptr,nullptr,nullptr);   // q|k fp8
  tr_pass1_kernel<<<cdiv(EE,16),BT,0,stream>>>(srcS,dstS,qk8,logitE);              // exp(logits)
  mgemm_kernel<64><<<dim3(GB,4),BT,0,stream>>>(x4b,wt+106496,tr_bv,nullptr,nullptr,v8,256,0,1,
                                               nullptr,nullptr,nullptr,nullptr);   // v fp8
  mgemm_kernel<64><<<dim3(GB,1),BT,0,stream>>>(x4b,wt+122880,tr_bs,skipf,nullptr,nullptr,64,0,0,
                                               nullptr,nullptr,nullptr,nullptr);   // skip f32
  tr_pass2_kernel<<<GW2,BT,0,stream>>>(rowptr,srcS,logitE,v8,skipf,x5b);
  // ---- EdgeConv ----
  mgemm_kernel<64><<<dim3(GB,2),BT,0,stream>>>(x5b,wt+126976,bPQ,nullptr,nullptr,PQ8,64,0,2,
                                               nullptr,nullptr,nullptr,nullptr);
  edgeconv3_kernel<<<EE/64,BT,0,stream>>>(PQ8,srcS,dstS,wt+135168,ec_b2,(unsigned*)nb5);
  // ---- pool + MLP ----
  pool_kernel<<<cdiv(NN,200),BT,0,stream>>>((unsigned*)nb5,batch,pooled);
  final_kernel<<<1,BT,0,stream>>>(pooled,batch,fc1_W,fc1_b,fc2_W,fc2_b,(float*)d_out);
}

// Round 10
// 724.530 us; speedup vs baseline: 1.0148x; 1.0026x over previous
//
#include <hip/hip_runtime.h>

#define NN 50000
#define EE 640000
#define GG 16
#define N64 (NN*64)

static inline int cdiv(int a,int b){return (a+b-1)/b;}

typedef __attribute__((ext_vector_type(8))) short bfrag;   // 8 bf16 (4 VGPR)
typedef __attribute__((ext_vector_type(4))) float ffrag;   // mfma accumulator
typedef __attribute__((ext_vector_type(2))) float f32x2;

__device__ __forceinline__ float lrelu(float x){ return x>0.f? x : 0.2f*x; }
__device__ __forceinline__ unsigned fenc(float f){
  unsigned u=__float_as_uint(f);
  return (u&0x80000000u)? ~u : (u|0x80000000u);
}
__device__ __forceinline__ float bf2f(unsigned short u){ return __uint_as_float(((unsigned)u)<<16); }
__device__ __forceinline__ unsigned short f2bf(float f){
  unsigned u=__float_as_uint(f);
  u += 0x7FFFu + ((u>>16)&1u);
  return (unsigned short)(u>>16);
}
// OCP e4m3 helpers (gfx950 hw cvt)
__device__ __forceinline__ unsigned char f2f8(float f){
  return (unsigned char)(__builtin_amdgcn_cvt_pk_fp8_f32(f,f,0,false)&0xff);
}
__device__ __forceinline__ void f8x4(unsigned u, float& e0,float& e1,float& e2,float& e3){
  f32x2 lo=__builtin_amdgcn_cvt_pk_f32_fp8((int)u,false);
  f32x2 hi=__builtin_amdgcn_cvt_pk_f32_fp8((int)u,true);
  e0=lo.x; e1=lo.y; e2=hi.x; e3=hi.y;
}
__device__ __forceinline__ float f8one(unsigned b){
  f32x2 lo=__builtin_amdgcn_cvt_pk_f32_fp8((int)b,false);
  return lo.x;
}
__device__ __forceinline__ float dot4f8(unsigned a, unsigned b){
  f32x2 al=__builtin_amdgcn_cvt_pk_f32_fp8((int)a,false);
  f32x2 ah=__builtin_amdgcn_cvt_pk_f32_fp8((int)a,true);
  f32x2 bl=__builtin_amdgcn_cvt_pk_f32_fp8((int)b,false);
  f32x2 bh=__builtin_amdgcn_cvt_pk_f32_fp8((int)b,true);
  return al.x*bl.x+al.y*bl.y+ah.x*bh.x+ah.y*bh.y;
}

__global__ void zero_kernel(unsigned* p, int n){
  int i=blockIdx.x*blockDim.x+threadIdx.x;
  if(i<n) p[i]=0u;
}

__global__ void hist_kernel(const int* __restrict__ dst, int* __restrict__ cnt){
  int e=blockIdx.x*blockDim.x+threadIdx.x;
  if(e<EE) atomicAdd(&cnt[dst[e]],1);
}

__global__ __launch_bounds__(1024) void scan1_kernel(const int* __restrict__ cnt,
    int* __restrict__ rowptr, int* __restrict__ bsum){
  __shared__ int wsum[16];
  int t=threadIdx.x, b=blockIdx.x;
  int i=b*1024+t;
  int v=(i<NN)?cnt[i]:0;
  int lane=t&63, w=t>>6;
  int inc=v;
  #pragma unroll
  for(int o=1;o<64;o<<=1){ int u=__shfl_up(inc,o,64); if(lane>=o) inc+=u; }
  if(lane==63) wsum[w]=inc;
  __syncthreads();
  if(t<16){
    int s=wsum[t];
    #pragma unroll
    for(int o=1;o<16;o<<=1){ int u=__shfl_up(s,o,16); if(t>=o) s+=u; }
    wsum[t]=s;
  }
  __syncthreads();
  int woff=(w>0)?wsum[w-1]:0;
  if(i<NN) rowptr[i]=woff+inc-v;
  if(t==1023) bsum[b]=wsum[15];
}

__global__ void scan2_kernel(const int* __restrict__ bsum, int* __restrict__ boff, int* __restrict__ rowptr, int nb){
  int t=threadIdx.x;
  int v=(t<nb)?bsum[t]:0;
  int inc=v;
  #pragma unroll
  for(int o=1;o<64;o<<=1){ int u=__shfl_up(inc,o,64); if(t>=o) inc+=u; }
  if(t<nb) boff[t]=inc-v;
  if(t==63) rowptr[NN]=inc;
}

// scan3: finalize rowptr, seed fillp=rowptr (fill uses atomicAdd directly), invdeg
__global__ void scan3_kernel(int* __restrict__ rowptr, const int* __restrict__ boff,
                             const int* __restrict__ cnt, int* __restrict__ fillp,
                             float* __restrict__ invdeg){
  int i=blockIdx.x*blockDim.x+threadIdx.x;
  if(i<NN){
    int rp=rowptr[i]+boff[i>>10];
    rowptr[i]=rp;
    fillp[i]=rp;
    invdeg[i]=1.f/fmaxf((float)cnt[i],1.f);
  }
}

// CSR fill: fillp pre-seeded with rowptr -> single atomic gives position; ONE int2
// scatter-store per edge (one dirty 64B line instead of two).
__global__ void fill_kernel(const int* __restrict__ src, const int* __restrict__ dst,
                            int* __restrict__ fillp, int2* __restrict__ sdtmp){
  int e=blockIdx.x*blockDim.x+threadIdx.x;
  if(e>=EE) return;
  int d=dst[e];
  int p=atomicAdd(&fillp[d],1);
  sdtmp[p]=make_int2(src[e],d);
}

// deinterleave sdtmp -> split srcS/dstS (sequential, keeps consumers on 4B streams)
__global__ void deint_kernel(const int2* __restrict__ sdtmp,
                             int* __restrict__ srcS, int* __restrict__ dstS){
  int i=blockIdx.x*blockDim.x+threadIdx.x;
  if(i>=EE) return;
  int2 v=sdtmp[i];
  srcS[i]=v.x; dstS[i]=v.y;
}

__global__ void cvtx_kernel(const float* __restrict__ x, unsigned short* __restrict__ xb){
  int i=blockIdx.x*blockDim.x+threadIdx.x;
  if(i>=NN*32) return;
  float4 v=*(const float4*)(x+(size_t)i*4);
  ushort4 o; o.x=f2bf(v.x); o.y=f2bf(v.y); o.z=f2bf(v.z); o.w=f2bf(v.w);
  *(ushort4*)(xb+(size_t)i*4)=o;
}

// weight prep: Wt[n][k]=W[k][n] bf16, all segments + bias packs
__global__ void prep_kernel(
    const float* __restrict__ g1W, const float* __restrict__ g2W,
    const float* __restrict__ giW1, const float* __restrict__ giW2,
    const float* __restrict__ s1Wl, const float* __restrict__ s1Wr,
    const float* __restrict__ s2Wl, const float* __restrict__ s2Wr,
    const float* __restrict__ Wq, const float* __restrict__ Wk,
    const float* __restrict__ Wv, const float* __restrict__ Ws,
    const float* __restrict__ ecW1, const float* __restrict__ ecW2,
    const float* __restrict__ bq, const float* __restrict__ bk, const float* __restrict__ eb1,
    unsigned short* __restrict__ wt, float* __restrict__ bqk, float* __restrict__ bPQ){
  int i=blockIdx.x*blockDim.x+threadIdx.x;
  if(i<32768){ int n=i>>7,k=i&127; wt[i]=f2bf(g1W[k*256+n]); return; } i-=32768;
  if(i<16384){ int n=i>>6,k=i&63; wt[32768+i]=f2bf(g2W[k*256+n]); return; } i-=16384;
  if(i<4096){ int n=i>>6,k=i&63; wt[49152+i]=f2bf(giW1[k*64+n]); return; } i-=4096;
  if(i<4096){ int n=i>>6,k=i&63; wt[53248+i]=f2bf(giW2[k*64+n]); return; } i-=4096;
  if(i<8192){ int n=i>>7,k=i&127; float v=(k<64)?s1Wl[k*64+n]:s1Wr[(k-64)*64+n];
              wt[57344+i]=f2bf(v); return; } i-=8192;
  if(i<8192){ int n=i>>7,k=i&127; float v=(k<64)?s2Wl[k*64+n]:s2Wr[(k-64)*64+n];
              wt[65536+i]=f2bf(v); return; } i-=8192;
  if(i<32768){ int n=i>>6,k=i&63; float v=(n<256)?Wq[k*256+n]:Wk[k*256+(n-256)];
               wt[73728+i]=f2bf(v); return; } i-=32768;
  if(i<16384){ int n=i>>6,k=i&63; wt[106496+i]=f2bf(Wv[k*256+n]); return; } i-=16384;
  if(i<4096){ int n=i>>6,k=i&63; wt[122880+i]=f2bf(Ws[k*64+n]); return; } i-=4096;
  if(i<8192){ int n=i>>6,k=i&63;
              float v=(n<64)?(ecW1[k*64+n]-ecW1[(64+k)*64+n]):ecW1[(64+k)*64+(n-64)];
              wt[126976+i]=f2bf(v); return; } i-=8192;
  if(i<4096){ int n=i>>6,k=i&63; wt[135168+i]=f2bf(ecW2[k*64+n]); return; } i-=4096;
  if(i<640){
    if(i<256) bqk[i]=bq[i];
    else if(i<512) bqk[i]=bk[i-256];
    else { int j=i-512; bPQ[j]=(j<64)?eb1[j]:0.f; }
  }
}

// bf16 MFMA GEMM with LDS A-staging: C[64x64 tile] = A[M,K]bf16 @ Wt[N,K]bf16^T (+bias)(relu)
template<int K>
__global__ __launch_bounds__(256) void mgemm_kernel(
    const unsigned short* __restrict__ A, const unsigned short* __restrict__ Wt,
    const float* __restrict__ bias,
    float* __restrict__ Cf, unsigned short* __restrict__ Cb, unsigned char* __restrict__ C8,
    int ldc, int relu_flag, int c8mode,
    const float* __restrict__ a_s, const float* __restrict__ a_d,
    float* __restrict__ lsO, float* __restrict__ ldO){
  __shared__ float lsP[2][4][64];
  __shared__ unsigned short As[64][K+8];
  const int m0=blockIdx.x*64;
  const int tid=threadIdx.x;
  #pragma unroll
  for(int it=0; it<K/32; ++it){
    int c = it*256 + tid;
    int row = c/(K/8), col8 = c%(K/8);
    int grow = m0+row; if(grow>=NN) grow=NN-1;
    *(bfrag*)&As[row][col8*8] = *(const bfrag*)(A+(size_t)grow*K+col8*8);
  }
  __syncthreads();
  const int w=tid>>6, l=tid&63, lo=l&15, quad=l>>4;
  const int colg=blockIdx.y*64 + w*16 + lo;
  const unsigned short* wrow=Wt+(size_t)colg*K+quad*8;
  ffrag acc[4];
  #pragma unroll
  for(int t=0;t<4;t++) acc[t]=(ffrag){0.f,0.f,0.f,0.f};
  #pragma unroll
  for(int kc=0;kc<K;kc+=32){
    bfrag b=*(const bfrag*)(wrow+kc);
    #pragma unroll
    for(int t=0;t<4;t++){
      bfrag a=*(const bfrag*)(&As[t*16+lo][kc+quad*8]);
      acc[t]=__builtin_amdgcn_mfma_f32_16x16x32_bf16(a,b,acc[t],0,0,0);
    }
  }
  float bv=bias?bias[colg]:0.f;
  float asv=0.f,adv=0.f;
  if(lsO){ asv=a_s[colg]; adv=a_d[colg]; }
  #pragma unroll
  for(int t=0;t<4;t++){
    #pragma unroll
    for(int r=0;r<4;r++){
      float v=acc[t][r]+bv;
      if(relu_flag) v=fmaxf(v,0.f);
      int row=m0+t*16+quad*4+r;
      if(row<NN){
        if(Cf) Cf[(size_t)row*ldc+colg]=v;
        if(Cb) Cb[(size_t)row*ldc+colg]=f2bf(v);
        if(C8){
          size_t idx;
          if(c8mode==1)      idx=(size_t)row*ldc + (((colg&63)<<2)|(colg>>6));
          else if(c8mode==2) idx=(size_t)((colg<64)?0:N64) + (size_t)row*64 + (colg&63);
          else               idx=(size_t)row*ldc + colg;
          C8[idx]=f2f8(v);
        }
      }
      if(lsO){
        float ps=v*asv, pd=v*adv;
        #pragma unroll
        for(int o=1;o<16;o<<=1){ ps+=__shfl_xor(ps,o,16); pd+=__shfl_xor(pd,o,16); }
        if(lo==0){ int lr=t*16+quad*4+r; lsP[0][w][lr]=ps; lsP[1][w][lr]=pd; }
      }
    }
  }
  if(lsO){
    __syncthreads();
    if(tid<64){
      int row=m0+tid;
      if(row<NN){
        lsO[(size_t)row*4+blockIdx.y]=lsP[0][0][tid]+lsP[0][1][tid]+lsP[0][2][tid]+lsP[0][3][tid];
        ldO[(size_t)row*4+blockIdx.y]=lsP[1][0][tid]+lsP[1][1][tid]+lsP[1][2][tid]+lsP[1][3][tid];
      }
    }
  }
}

// GAT edge exps: eE[j] = exp(lrelu(ls[src]+ld[dst])), one thread per edge (computed ONCE).
__global__ void gat_exp_kernel(const int* __restrict__ srcS, const int* __restrict__ dstS,
    const float* __restrict__ ls4, const float* __restrict__ ld4, float* __restrict__ eE){
  int j=blockIdx.x*blockDim.x+threadIdx.x;
  if(j>=EE) return;
  int s=srcS[j], d=dstS[j];
  const float4 a=*(const float4*)(ls4+(size_t)4*s);
  const float4 b=*(const float4*)(ld4+(size_t)4*d);
  *(float4*)(eE+(size_t)4*j)=make_float4(
    __expf(lrelu(a.x+b.x)),__expf(lrelu(a.y+b.y)),
    __expf(lrelu(a.z+b.z)),__expf(lrelu(a.w+b.w)));
}

// single-pass GAT: 1 WAVE PER NODE (4 nodes/block), no LDS reduction, no barrier.
// Unroll-8 lead round (8 gathers in flight), then 4, then scalar tail. fp8 h gather. (R7 form)
__global__ __launch_bounds__(256) void gat1p_kernel(const unsigned char* __restrict__ h8,
    const int* __restrict__ rowptr, const int* __restrict__ srcS,
    const float* __restrict__ eE,
    const float* __restrict__ ls4, const float* __restrict__ ld4,
    const float* __restrict__ bias, unsigned short* __restrict__ outb,
    unsigned char* __restrict__ out8){
  int w=threadIdx.x>>6, lane=threadIdx.x&63;
  int n=blockIdx.x*4+w;
  if(n>=NN) return;
  int r0=rowptr[n], r1=rowptr[n+1];
  const float4 ldv=*(const float4*)(ld4+(size_t)4*n);
  const float4 lsv=*(const float4*)(ls4+(size_t)4*n);
  float z0=__expf(lrelu(lsv.x+ldv.x)), z1=__expf(lrelu(lsv.y+ldv.y));
  float z2=__expf(lrelu(lsv.z+ldv.z)), z3=__expf(lrelu(lsv.w+ldv.w));
  float h0,h1,h2,h3;
  f8x4(*(const unsigned*)(h8+(size_t)n*256+lane*4),h0,h1,h2,h3);
  float a0=z0*h0, a1=z1*h1, a2=z2*h2, a3=z3*h3;
  int j=r0;
  for(; j+7<r1; j+=8){
    int s0=srcS[j],   s1=srcS[j+1], s2=srcS[j+2], s3=srcS[j+3];
    int s4=srcS[j+4], s5=srcS[j+5], s6=srcS[j+6], s7=srcS[j+7];
    const float4 E0=*(const float4*)(eE+(size_t)4*j);
    const float4 E1=*(const float4*)(eE+(size_t)4*(j+1));
    const float4 E2=*(const float4*)(eE+(size_t)4*(j+2));
    const float4 E3=*(const float4*)(eE+(size_t)4*(j+3));
    const float4 E4=*(const float4*)(eE+(size_t)4*(j+4));
    const float4 E5=*(const float4*)(eE+(size_t)4*(j+5));
    const float4 E6=*(const float4*)(eE+(size_t)4*(j+6));
    const float4 E7=*(const float4*)(eE+(size_t)4*(j+7));
    unsigned u0=*(const unsigned*)(h8+(size_t)s0*256+lane*4);
    unsigned u1=*(const unsigned*)(h8+(size_t)s1*256+lane*4);
    unsigned u2=*(const unsigned*)(h8+(size_t)s2*256+lane*4);
    unsigned u3=*(const unsigned*)(h8+(size_t)s3*256+lane*4);
    unsigned u4=*(const unsigned*)(h8+(size_t)s4*256+lane*4);
    unsigned u5=*(const unsigned*)(h8+(size_t)s5*256+lane*4);
    unsigned u6=*(const unsigned*)(h8+(size_t)s6*256+lane*4);
    unsigned u7=*(const unsigned*)(h8+(size_t)s7*256+lane*4);
    float p0,p1,p2,p3;
    f8x4(u0,p0,p1,p2,p3); a0+=E0.x*p0; a1+=E0.y*p1; a2+=E0.z*p2; a3+=E0.w*p3;
    f8x4(u1,p0,p1,p2,p3); a0+=E1.x*p0; a1+=E1.y*p1; a2+=E1.z*p2; a3+=E1.w*p3;
    f8x4(u2,p0,p1,p2,p3); a0+=E2.x*p0; a1+=E2.y*p1; a2+=E2.z*p2; a3+=E2.w*p3;
    f8x4(u3,p0,p1,p2,p3); a0+=E3.x*p0; a1+=E3.y*p1; a2+=E3.z*p2; a3+=E3.w*p3;
    f8x4(u4,p0,p1,p2,p3); a0+=E4.x*p0; a1+=E4.y*p1; a2+=E4.z*p2; a3+=E4.w*p3;
    f8x4(u5,p0,p1,p2,p3); a0+=E5.x*p0; a1+=E5.y*p1; a2+=E5.z*p2; a3+=E5.w*p3;
    f8x4(u6,p0,p1,p2,p3); a0+=E6.x*p0; a1+=E6.y*p1; a2+=E6.z*p2; a3+=E6.w*p3;
    f8x4(u7,p0,p1,p2,p3); a0+=E7.x*p0; a1+=E7.y*p1; a2+=E7.z*p2; a3+=E7.w*p3;
    z0+=((E0.x+E1.x)+(E2.x+E3.x))+((E4.x+E5.x)+(E6.x+E7.x));
    z1+=((E0.y+E1.y)+(E2.y+E3.y))+((E4.y+E5.y)+(E6.y+E7.y));
    z2+=((E0.z+E1.z)+(E2.z+E3.z))+((E4.z+E5.z)+(E6.z+E7.z));
    z3+=((E0.w+E1.w)+(E2.w+E3.w))+((E4.w+E5.w)+(E6.w+E7.w));
  }
  for(; j+3<r1; j+=4){
    int s0=srcS[j], s1=srcS[j+1], s2=srcS[j+2], s3=srcS[j+3];
    const float4 E0=*(const float4*)(eE+(size_t)4*j);
    const float4 E1=*(const float4*)(eE+(size_t)4*(j+1));
    const float4 E2=*(const float4*)(eE+(size_t)4*(j+2));
    const float4 E3=*(const float4*)(eE+(size_t)4*(j+3));
    unsigned u0=*(const unsigned*)(h8+(size_t)s0*256+lane*4);
    unsigned u1=*(const unsigned*)(h8+(size_t)s1*256+lane*4);
    unsigned u2=*(const unsigned*)(h8+(size_t)s2*256+lane*4);
    unsigned u3=*(const unsigned*)(h8+(size_t)s3*256+lane*4);
    float p0,p1,p2,p3;
    f8x4(u0,p0,p1,p2,p3); a0+=E0.x*p0; a1+=E0.y*p1; a2+=E0.z*p2; a3+=E0.w*p3;
    f8x4(u1,p0,p1,p2,p3); a0+=E1.x*p0; a1+=E1.y*p1; a2+=E1.z*p2; a3+=E1.w*p3;
    f8x4(u2,p0,p1,p2,p3); a0+=E2.x*p0; a1+=E2.y*p1; a2+=E2.z*p2; a3+=E2.w*p3;
    f8x4(u3,p0,p1,p2,p3); a0+=E3.x*p0; a1+=E3.y*p1; a2+=E3.z*p2; a3+=E3.w*p3;
    z0+=(E0.x+E1.x)+(E2.x+E3.x); z1+=(E0.y+E1.y)+(E2.y+E3.y);
    z2+=(E0.z+E1.z)+(E2.z+E3.z); z3+=(E0.w+E1.w)+(E2.w+E3.w);
  }
  for(; j<r1; j++){
    int s0=srcS[j];
    const float4 E0=*(const float4*)(eE+(size_t)4*j);
    unsigned u0=*(const unsigned*)(h8+(size_t)s0*256+lane*4);
    float p0,p1,p2,p3; f8x4(u0,p0,p1,p2,p3);
    z0+=E0.x; z1+=E0.y; z2+=E0.z; z3+=E0.w;
    a0+=E0.x*p0; a1+=E0.y*p1; a2+=E0.z*p2; a3+=E0.w*p3;
  }
  float r=0.25f*(a0/(z0+1e-16f)+a1/(z1+1e-16f)+a2/(z2+1e-16f)+a3/(z3+1e-16f))+bias[lane];
  float rr=fmaxf(r,0.f);
  outb[(size_t)n*64+lane]=f2bf(rr);
  if(out8) out8[(size_t)n*64+lane]=f2f8(rr);
}

// GIN: self(bf16) + sum of neighbors (fp8 L2-resident gather), unroll 4
__global__ __launch_bounds__(256) void agg_kernel(const unsigned short* __restrict__ xin,
    const unsigned char* __restrict__ xin8,
    const int* __restrict__ rowptr, const int* __restrict__ srcS,
    unsigned short* __restrict__ out){
  int n=blockIdx.x*4+(threadIdx.x>>6);
  int lane=threadIdx.x&63;
  if(n>=NN) return;
  int r0=rowptr[n], r1=rowptr[n+1];
  float acc=bf2f(xin[(size_t)n*64+lane]);
  int j=r0;
  for(; j+3<r1; j+=4){
    int s0=srcS[j], s1=srcS[j+1], s2=srcS[j+2], s3=srcS[j+3];
    unsigned b0=xin8[(size_t)s0*64+lane];
    unsigned b1=xin8[(size_t)s1*64+lane];
    unsigned b2=xin8[(size_t)s2*64+lane];
    unsigned b3=xin8[(size_t)s3*64+lane];
    acc+=(f8one(b0)+f8one(b1))+(f8one(b2)+f8one(b3));
  }
  for(; j<r1; j++) acc+=f8one(xin8[(size_t)srcS[j]*64+lane]);
  out[(size_t)n*64+lane]=f2bf(acc);
}

// SAGE staging: out128b[n]=[mean_neigh(fp8 gather), self(bf16)] bf16, unroll 4
__global__ __launch_bounds__(256) void agg2_kernel(const unsigned short* __restrict__ xin,
    const unsigned char* __restrict__ xin8,
    const int* __restrict__ rowptr, const int* __restrict__ srcS,
    const float* __restrict__ invdeg, unsigned short* __restrict__ out128b){
  int n=blockIdx.x*4+(threadIdx.x>>6);
  int lane=threadIdx.x&63;
  if(n>=NN) return;
  int r0=rowptr[n], r1=rowptr[n+1];
  float acc=0.f;
  int j=r0;
  for(; j+3<r1; j+=4){
    int s0=srcS[j], s1=srcS[j+1], s2=srcS[j+2], s3=srcS[j+3];
    unsigned b0=xin8[(size_t)s0*64+lane];
    unsigned b1=xin8[(size_t)s1*64+lane];
    unsigned b2=xin8[(size_t)s2*64+lane];
    unsigned b3=xin8[(size_t)s3*64+lane];
    acc+=(f8one(b0)+f8one(b1))+(f8one(b2)+f8one(b3));
  }
  for(; j<r1; j++) acc+=f8one(xin8[(size_t)srcS[j]*64+lane]);
  out128b[(size_t)n*128+lane]=f2bf(acc*invdeg[n]);
  out128b[(size_t)n*128+64+lane]=xin[(size_t)n*64+lane];
}

// TR pass1 (edge-parallel SDDMM): qk8 [N,512] fp8 (q|k head-major); stores EXP of logits.
__global__ __launch_bounds__(256) void tr_pass1_kernel(const int* __restrict__ srcS, const int* __restrict__ dstS,
    const unsigned char* __restrict__ qk8, float* __restrict__ lg){
  int e=blockIdx.x*16+(threadIdx.x>>4);
  int t=threadIdx.x&15;
  if(e>=EE) return;
  int s=srcS[e], d=dstS[e];
  const unsigned char* qd=qk8+(size_t)d*512+t*4;
  const unsigned char* ks=qk8+(size_t)s*512+256+t*4;
  unsigned ku0=*(const unsigned*)(ks);
  unsigned ku1=*(const unsigned*)(ks+64);
  unsigned ku2=*(const unsigned*)(ks+128);
  unsigned ku3=*(const unsigned*)(ks+192);
  unsigned qu0=*(const unsigned*)(qd);
  unsigned qu1=*(const unsigned*)(qd+64);
  unsigned qu2=*(const unsigned*)(qd+128);
  unsigned qu3=*(const unsigned*)(qd+192);
  float v0=dot4f8(ku0,qu0);
  float v1=dot4f8(ku1,qu1);
  float v2=dot4f8(ku2,qu2);
  float v3=dot4f8(ku3,qu3);
  #pragma unroll
  for(int o=1;o<16;o<<=1){
    v0+=__shfl_xor(v0,o,16); v1+=__shfl_xor(v1,o,16);
    v2+=__shfl_xor(v2,o,16); v3+=__shfl_xor(v3,o,16);
  }
  if(t==0)
    *(float4*)(lg+(size_t)4*e)=make_float4(__expf(v0*0.125f),__expf(v1*0.125f),
                                           __expf(v2*0.125f),__expf(v3*0.125f));
}

// TR pass2: 1 WAVE PER NODE (4 nodes/block), unroll-8/4/tail; fp8 v-gather + skip + relu (R7 form)
__global__ __launch_bounds__(256) void tr_pass2_kernel(const int* __restrict__ rowptr, const int* __restrict__ srcS,
    const float* __restrict__ lg,
    const unsigned char* __restrict__ v8, const float* __restrict__ skip, unsigned short* __restrict__ x5b){
  int w=threadIdx.x>>6, lane=threadIdx.x&63;
  int n=blockIdx.x*4+w;
  if(n>=NN) return;
  int r0=rowptr[n], r1=rowptr[n+1];
  float z0=0.f,z1=0.f,z2=0.f,z3=0.f;
  float a0=0.f,a1=0.f,a2=0.f,a3=0.f;
  int j=r0;
  for(; j+7<r1; j+=8){
    int s0=srcS[j],   s1=srcS[j+1], s2=srcS[j+2], s3=srcS[j+3];
    int s4=srcS[j+4], s5=srcS[j+5], s6=srcS[j+6], s7=srcS[j+7];
    const float4 E0=*(const float4*)(lg+(size_t)4*j);
    const float4 E1=*(const float4*)(lg+(size_t)4*(j+1));
    const float4 E2=*(const float4*)(lg+(size_t)4*(j+2));
    const float4 E3=*(const float4*)(lg+(size_t)4*(j+3));
    const float4 E4=*(const float4*)(lg+(size_t)4*(j+4));
    const float4 E5=*(const float4*)(lg+(size_t)4*(j+5));
    const float4 E6=*(const float4*)(lg+(size_t)4*(j+6));
    const float4 E7=*(const float4*)(lg+(size_t)4*(j+7));
    unsigned u0=*(const unsigned*)(v8+(size_t)s0*256+lane*4);
    unsigned u1=*(const unsigned*)(v8+(size_t)s1*256+lane*4);
    unsigned u2=*(const unsigned*)(v8+(size_t)s2*256+lane*4);
    unsigned u3=*(const unsigned*)(v8+(size_t)s3*256+lane*4);
    unsigned u4=*(const unsigned*)(v8+(size_t)s4*256+lane*4);
    unsigned u5=*(const unsigned*)(v8+(size_t)s5*256+lane*4);
    unsigned u6=*(const unsigned*)(v8+(size_t)s6*256+lane*4);
    unsigned u7=*(const unsigned*)(v8+(size_t)s7*256+lane*4);
    float p0,p1,p2,p3;
    f8x4(u0,p0,p1,p2,p3); a0+=E0.x*p0; a1+=E0.y*p1; a2+=E0.z*p2; a3+=E0.w*p3;
    f8x4(u1,p0,p1,p2,p3); a0+=E1.x*p0; a1+=E1.y*p1; a2+=E1.z*p2; a3+=E1.w*p3;
    f8x4(u2,p0,p1,p2,p3); a0+=E2.x*p0; a1+=E2.y*p1; a2+=E2.z*p2; a3+=E2.w*p3;
    f8x4(u3,p0,p1,p2,p3); a0+=E3.x*p0; a1+=E3.y*p1; a2+=E3.z*p2; a3+=E3.w*p3;
    f8x4(u4,p0,p1,p2,p3); a0+=E4.x*p0; a1+=E4.y*p1; a2+=E4.z*p2; a3+=E4.w*p3;
    f8x4(u5,p0,p1,p2,p3); a0+=E5.x*p0; a1+=E5.y*p1; a2+=E5.z*p2; a3+=E5.w*p3;
    f8x4(u6,p0,p1,p2,p3); a0+=E6.x*p0; a1+=E6.y*p1; a2+=E6.z*p2; a3+=E6.w*p3;
    f8x4(u7,p0,p1,p2,p3); a0+=E7.x*p0; a1+=E7.y*p1; a2+=E7.z*p2; a3+=E7.w*p3;
    z0+=((E0.x+E1.x)+(E2.x+E3.x))+((E4.x+E5.x)+(E6.x+E7.x));
    z1+=((E0.y+E1.y)+(E2.y+E3.y))+((E4.y+E5.y)+(E6.y+E7.y));
    z2+=((E0.z+E1.z)+(E2.z+E3.z))+((E4.z+E5.z)+(E6.z+E7.z));
    z3+=((E0.w+E1.w)+(E2.w+E3.w))+((E4.w+E5.w)+(E6.w+E7.w));
  }
  for(; j+3<r1; j+=4){
    int s0=srcS[j], s1=srcS[j+1], s2=srcS[j+2], s3=srcS[j+3];
    const float4 E0=*(const float4*)(lg+(size_t)4*j);
    const float4 E1=*(const float4*)(lg+(size_t)4*(j+1));
    const float4 E2=*(const float4*)(lg+(size_t)4*(j+2));
    const float4 E3=*(const float4*)(lg+(size_t)4*(j+3));
    unsigned u0=*(const unsigned*)(v8+(size_t)s0*256+lane*4);
    unsigned u1=*(const unsigned*)(v8+(size_t)s1*256+lane*4);
    unsigned u2=*(const unsigned*)(v8+(size_t)s2*256+lane*4);
    unsigned u3=*(const unsigned*)(v8+(size_t)s3*256+lane*4);
    float p0,p1,p2,p3;
    f8x4(u0,p0,p1,p2,p3); a0+=E0.x*p0; a1+=E0.y*p1; a2+=E0.z*p2; a3+=E0.w*p3;
    f8x4(u1,p0,p1,p2,p3); a0+=E1.x*p0; a1+=E1.y*p1; a2+=E1.z*p2; a3+=E1.w*p3;
    f8x4(u2,p0,p1,p2,p3); a0+=E2.x*p0; a1+=E2.y*p1; a2+=E2.z*p2; a3+=E2.w*p3;
    f8x4(u3,p0,p1,p2,p3); a0+=E3.x*p0; a1+=E3.y*p1; a2+=E3.z*p2; a3+=E3.w*p3;
    z0+=(E0.x+E1.x)+(E2.x+E3.x); z1+=(E0.y+E1.y)+(E2.y+E3.y);
    z2+=(E0.z+E1.z)+(E2.z+E3.z); z3+=(E0.w+E1.w)+(E2.w+E3.w);
  }
  for(; j<r1; j++){
    int s0=srcS[j];
    const float4 E0=*(const float4*)(lg+(size_t)4*j);
    unsigned u0=*(const unsigned*)(v8+(size_t)s0*256+lane*4);
    float p0,p1,p2,p3; f8x4(u0,p0,p1,p2,p3);
    z0+=E0.x; z1+=E0.y; z2+=E0.z; z3+=E0.w;
    a0+=E0.x*p0; a1+=E0.y*p1; a2+=E0.z*p2; a3+=E0.w*p3;
  }
  float t=0.25f*(a0/(z0+1e-16f)+a1/(z1+1e-16f)+a2/(z2+1e-16f)+a3/(z3+1e-16f))+skip[(size_t)n*64+lane];
  x5b[(size_t)n*64+lane]=f2bf(fmaxf(t,0.f));
}

// EdgeConv: fp8 split P/Q gather -> LDS bf16 hidden -> MFMA GEMM2 -> parallel segmented max.
__global__ __launch_bounds__(256) void edgeconv3_kernel(
    const unsigned char* __restrict__ PQ8,
    const int* __restrict__ srcS, const int* __restrict__ dstS,
    const unsigned short* __restrict__ W2t, const float* __restrict__ b2,
    unsigned* __restrict__ emax){
  __shared__ __align__(16) unsigned char smem[64*68*4];   // 17408 B union
  __shared__ int dstL[64];
  unsigned short (*Hs)[72]=(unsigned short(*)[72])smem;   // 9216 B live phase 1-2
  float (*As)[68]=(float(*)[68])smem;                     // 17408 B live phase 3-4
  const unsigned char* P8=PQ8;
  const unsigned char* Q8=PQ8+(size_t)N64;
  const int e0=blockIdx.x*64;
  const int tid=threadIdx.x;
  if(tid<64) dstL[tid]=dstS[e0+tid];
  #pragma unroll
  for(int it=0;it<4;it++){
    int linear=it*1024+tid*4;
    int m=linear>>6, k=linear&63;
    int e=e0+m;
    int dn=dstS[e], sn=srcS[e];
    unsigned pu=*(const unsigned*)(P8+(size_t)dn*64+k);
    unsigned qu=*(const unsigned*)(Q8+(size_t)sn*64+k);
    float p0,p1,p2,p3; f8x4(pu,p0,p1,p2,p3);
    float q0,q1,q2,q3; f8x4(qu,q0,q1,q2,q3);
    ushort4 hh;
    hh.x=f2bf(fmaxf(p0+q0,0.f));
    hh.y=f2bf(fmaxf(p1+q1,0.f));
    hh.z=f2bf(fmaxf(p2+q2,0.f));
    hh.w=f2bf(fmaxf(p3+q3,0.f));
    *(ushort4*)&Hs[m][k]=hh;
  }
  __syncthreads();
  const int w=tid>>6, l=tid&63, lo=l&15, quad=l>>4;
  const int colg=w*16+lo;
  ffrag acc[4];
  #pragma unroll
  for(int t=0;t<4;t++) acc[t]=(ffrag){0.f,0.f,0.f,0.f};
  #pragma unroll
  for(int kc=0;kc<64;kc+=32){
    bfrag b=*(const bfrag*)(W2t+(size_t)colg*64+kc+quad*8);
    #pragma unroll
    for(int t=0;t<4;t++){
      bfrag a=*(const bfrag*)(&Hs[t*16+lo][kc+quad*8]);
      acc[t]=__builtin_amdgcn_mfma_f32_16x16x32_bf16(a,b,acc[t],0,0,0);
    }
  }
  __syncthreads();                 // all Hs reads done before As overwrites the union
  float bv=b2[colg];
  #pragma unroll
  for(int t=0;t<4;t++)
    #pragma unroll
    for(int r=0;r<4;r++)
      As[t*16+quad*4+r][colg]=acc[t][r]+bv;
  __syncthreads();
  {
    const int c=tid&63, qtr=tid>>6, base=qtr*16;
    const int dFirst=dstL[base], dLast=dstL[base+15];
    int dprev=dFirst;
    float mx=As[base][c];
    #pragma unroll
    for(int i=1;i<16;i++){
      int dn=dstL[base+i];
      float v=As[base+i][c];
      if(dn!=dprev){
        unsigned* addr=&emax[(size_t)dprev*64+c];
        unsigned enc=fenc(mx);
        if(dprev!=dFirst && dprev!=dLast) *addr=enc;
        else atomicMax(addr,enc);
        dprev=dn; mx=v;
      }else mx=fmaxf(mx,v);
    }
    unsigned* addr=&emax[(size_t)dprev*64+c];
    unsigned enc=fenc(mx);
    if(dprev!=dFirst && dprev!=dLast) *addr=enc;
    else atomicMax(addr,enc);
  }
}

__global__ __launch_bounds__(256) void pool_kernel(const unsigned* __restrict__ emax, const int* __restrict__ batch,
                                                   float* __restrict__ pooled){
  const int NB=200;
  int base=blockIdx.x*NB;
  int lane=threadIdx.x&63;
  int wsub=threadIdx.x>>6;
  float acc=0.f; int curg=-1;
  for(int idx=wsub; idx<NB; idx+=4){
    int n=base+idx;
    if(n>=NN) break;
    int g=batch[n];
    if(g!=curg){
      if(curg>=0) atomicAdd(&pooled[curg*64+lane],acc);
      acc=0.f; curg=g;
    }
    unsigned u=emax[(size_t)n*64+lane];
    acc+=(u>=0x80000000u)? __uint_as_float(u&0x7fffffffu) : 0.f;
  }
  if(curg>=0) atomicAdd(&pooled[curg*64+lane],acc);
}

__global__ __launch_bounds__(256) void final_kernel(const float* __restrict__ pooled, const int* __restrict__ batch,
    const float* __restrict__ fc1W, const float* __restrict__ fc1b,
    const float* __restrict__ fc2W, const float* __restrict__ fc2b,
    float* __restrict__ out){
  __shared__ float gm[16][64];
  __shared__ float t1[16][64];
  __shared__ int cgs[17];
  int t=threadIdx.x;
  if(t<17){
    int lo=0, hi=NN;
    while(lo<hi){ int mid=(lo+hi)>>1; if(batch[mid]<t) lo=mid+1; else hi=mid; }
    cgs[t]=lo;
  }
  __syncthreads();
  for(int r=0;r<4;r++){
    int idx=r*256+t; int g=idx>>6, d=idx&63;
    float c=(float)(cgs[g+1]-cgs[g]);
    gm[g][d]=pooled[idx]/fmaxf(c,1.f);
  }
  __syncthreads();
  for(int r=0;r<4;r++){
    int idx=r*256+t; int g=idx>>6, d=idx&63;
    float a=fc1b[d];
    for(int k2=0;k2<64;k2++) a+=gm[g][k2]*fc1W[k2*64+d];
    t1[g][d]=fmaxf(a,0.f);
  }
  __syncthreads();
  for(int r=0;r<4;r++){
    int idx=r*256+t; int g=idx>>6, d=idx&63;
    float a=fc2b[d];
    for(int k2=0;k2<64;k2++) a+=t1[g][k2]*fc2W[k2*64+d];
    out[idx]=a;
  }
}

extern "C" void kernel_launch(void* const* d_in, const int* in_sizes, int n_in,
                              void* d_out, int out_size, void* d_ws, size_t ws_size,
                              hipStream_t stream){
  const float* x       =(const float*)d_in[0];
  const int*   ei      =(const int*)  d_in[1];
  const int*   src     =ei;
  const int*   dst     =ei+EE;
  const int*   batch   =(const int*)  d_in[2];
  const float* gat1_W  =(const float*)d_in[3];
  const float* gat1_as =(const float*)d_in[4];
  const float* gat1_ad =(const float*)d_in[5];
  const float* gat1_b  =(const float*)d_in[6];
  const float* gat2_W  =(const float*)d_in[7];
  const float* gat2_as =(const float*)d_in[8];
  const float* gat2_ad =(const float*)d_in[9];
  const float* gat2_b  =(const float*)d_in[10];
  const float* gin_W1  =(const float*)d_in[11];
  const float* gin_b1  =(const float*)d_in[12];
  const float* gin_W2  =(const float*)d_in[13];
  const float* gin_b2  =(const float*)d_in[14];
  const float* sage1_Wl=(const float*)d_in[15];
  const float* sage1_bl=(const float*)d_in[16];
  const float* sage1_Wr=(const float*)d_in[17];
  const float* sage2_Wl=(const float*)d_in[18];
  const float* sage2_bl=(const float*)d_in[19];
  const float* sage2_Wr=(const float*)d_in[20];
  const float* tr_Wq   =(const float*)d_in[21];
  const float* tr_bq   =(const float*)d_in[22];
  const float* tr_Wk   =(const float*)d_in[23];
  const float* tr_bk   =(const float*)d_in[24];
  const float* tr_Wv   =(const float*)d_in[25];
  const float* tr_bv   =(const float*)d_in[26];
  const float* tr_Ws   =(const float*)d_in[27];
  const float* tr_bs   =(const float*)d_in[28];
  const float* ec_W1   =(const float*)d_in[29];
  const float* ec_b1   =(const float*)d_in[30];
  const float* ec_W2   =(const float*)d_in[31];
  const float* ec_b2   =(const float*)d_in[32];
  const float* fc1_W   =(const float*)d_in[33];
  const float* fc1_b   =(const float*)d_in[34];
  const float* fc2_W   =(const float*)d_in[35];
  const float* fc2_b   =(const float*)d_in[36];

  // ---- workspace layout ----
  float* base=(float*)d_ws;
  size_t off=0;
  auto alloc=[&](size_t n){ float* p=base+off; off+=n; return p; };
  float* A_big =alloc((size_t)NN*256);
  float* nb0   =alloc(N64);
  float* nb1   =alloc(N64);
  float* nb2   =alloc(N64);
  float* nb3   =alloc(N64);
  float* nb4   =alloc(N64);
  float* nb5   =alloc(N64);                // emax
  float* logitE=alloc((size_t)EE*4);
  float* ls    =alloc(NN*4);
  float* ldb   =alloc(NN*4);
  float* invdeg=alloc(NN);
  float* pooled=alloc(GG*64);
  float* wbuf  =alloc(70000);
  float* bbuf  =alloc(640);
  int* ibase=(int*)(base+off);             // 8B-aligned (all allocs even)
  int2* sdtmp=(int2*)ibase;                // [EE] interleaved scratch (2*EE ints)
  int* srcS  =ibase+2*EE;
  int* dstS  =ibase+3*EE;
  int* cnt   =ibase+4*EE;
  int* fillp =ibase+4*EE+NN;
  int* rowptr=ibase+4*EE+2*NN;
  int* bsum  =ibase+4*EE+3*NN+8;
  int* boff  =bsum+64;

  const int BT=256;
  const int NSB=cdiv(NN,1024);
  // ---- zero init ----
  zero_kernel<<<cdiv(NN,BT),BT,0,stream>>>((unsigned*)cnt,NN);
  zero_kernel<<<cdiv(GG*64,BT),BT,0,stream>>>((unsigned*)pooled,GG*64);
  zero_kernel<<<cdiv(N64,BT),BT,0,stream>>>((unsigned*)nb5,N64);
  // ---- CSR ----
  hist_kernel<<<cdiv(EE,BT),BT,0,stream>>>(dst,cnt);
  scan1_kernel<<<NSB,1024,0,stream>>>(cnt,rowptr,bsum);
  scan2_kernel<<<1,64,0,stream>>>(bsum,boff,rowptr,NSB);
  scan3_kernel<<<cdiv(NN,BT),BT,0,stream>>>(rowptr,boff,cnt,fillp,invdeg);
  fill_kernel<<<cdiv(EE,BT),BT,0,stream>>>(src,dst,fillp,sdtmp);
  deint_kernel<<<cdiv(EE,BT),BT,0,stream>>>(sdtmp,srcS,dstS);

  const int GB=cdiv(NN,64);        // 782
  const int GW=cdiv(NN,4);         // 12500

  unsigned short* wt =(unsigned short*)wbuf;
  float* bqk=bbuf;
  float* bPQ=bbuf+512;
  unsigned char*  Abc  =(unsigned char*)A_big;                 // 51.2MB scratch
  unsigned char*  h8   =Abc;                                   // [N][64][4] fp8, 12.8MB
  unsigned char*  qk8  =Abc;                                   // [N][512]  fp8, 25.6MB
  unsigned char*  PQ8  =Abc;                                   // P [N][64] + Q [N][64], 6.4MB
  unsigned short* xb   =(unsigned short*)A_big+(size_t)NN*256; // bf16 x @25.6MB, 25.6MB
  unsigned char*  x2f8 =Abc+26000000;                          // 3.2MB (xb dead by then)
  unsigned char*  x3f8 =Abc+30000000;                          // 3.2MB
  unsigned char*  xsf8 =Abc+34000000;                          // 3.2MB
  unsigned short* xcatb=(unsigned short*)A_big;                // [N][128] bf16, 12.8MB
  unsigned short* x1b  =(unsigned short*)nb0;
  unsigned short* x2b  =(unsigned short*)nb1;
  unsigned short* tb   =(unsigned short*)nb2;
  unsigned short* hb3  =(unsigned short*)nb3;
  unsigned short* x3b  =(unsigned short*)nb1;
  unsigned short* xsb  =(unsigned short*)nb2;
  unsigned short* x4b  =(unsigned short*)nb0;
  unsigned char*  v8   =(unsigned char*)nb1;                   // [N][64][4] fp8
  unsigned short* x5b  =(unsigned short*)nb4;
  float* skipf=nb3;

  // ---- prep ----
  prep_kernel<<<cdiv(139904,BT),BT,0,stream>>>(gat1_W,gat2_W,gin_W1,gin_W2,
      sage1_Wl,sage1_Wr,sage2_Wl,sage2_Wr,tr_Wq,tr_Wk,tr_Wv,tr_Ws,ec_W1,ec_W2,
      tr_bq,tr_bk,ec_b1,wt,bqk,bPQ);
  cvtx_kernel<<<cdiv(NN*32,BT),BT,0,stream>>>(x,xb);

  // ---- GAT1 ----
  mgemm_kernel<128><<<dim3(GB,4),BT,0,stream>>>(xb,wt,nullptr,nullptr,nullptr,h8,256,0,1,
                                                gat1_as,gat1_ad,ls,ldb);
  gat_exp_kernel<<<cdiv(EE,BT),BT,0,stream>>>(srcS,dstS,ls,ldb,logitE);
  gat1p_kernel<<<GW,BT,0,stream>>>(h8,rowptr,srcS,logitE,ls,ldb,gat1_b,x1b,nullptr);
  // ---- GAT2 ----
  mgemm_kernel<64><<<dim3(GB,4),BT,0,stream>>>(x1b,wt+32768,nullptr,nullptr,nullptr,h8,256,0,1,
                                               gat2_as,gat2_ad,ls,ldb);
  gat_exp_kernel<<<cdiv(EE,BT),BT,0,stream>>>(srcS,dstS,ls,ldb,logitE);
  gat1p_kernel<<<GW,BT,0,stream>>>(h8,rowptr,srcS,logitE,ls,ldb,gat2_b,x2b,x2f8);
  // ---- GIN ----
  agg_kernel<<<GW,BT,0,stream>>>(x2b,x2f8,rowptr,srcS,tb);
  mgemm_kernel<64><<<dim3(GB,1),BT,0,stream>>>(tb,wt+49152,gin_b1,nullptr,hb3,nullptr,64,1,0,
                                               nullptr,nullptr,nullptr,nullptr);
  mgemm_kernel<64><<<dim3(GB,1),BT,0,stream>>>(hb3,wt+53248,gin_b2,nullptr,x3b,x3f8,64,1,0,
                                               nullptr,nullptr,nullptr,nullptr);
  // ---- SAGE1 ----
  agg2_kernel<<<GW,BT,0,stream>>>(x3b,x3f8,rowptr,srcS,invdeg,xcatb);
  mgemm_kernel<128><<<dim3(GB,1),BT,0,stream>>>(xcatb,wt+57344,sage1_bl,nullptr,xsb,xsf8,64,1,0,
                                                nullptr,nullptr,nullptr,nullptr);
  // ---- SAGE2 ----
  agg2_kernel<<<GW,BT,0,stream>>>(xsb,xsf8,rowptr,srcS,invdeg,xcatb);
  mgemm_kernel<128><<<dim3(GB,1),BT,0,stream>>>(xcatb,wt+65536,sage2_bl,nullptr,x4b,nullptr,64,1,0,
                                                nullptr,nullptr,nullptr,nullptr);
  // ---- TransformerConv ----
  mgemm_kernel<64><<<dim3(GB,8),BT,0,stream>>>(x4b,wt+73728,bqk,nullptr,nullptr,qk8,512,0,0,
                                               nullptr,nullptr,nullptr,nullptr);   // q|k fp8
  tr_pass1_kernel<<<cdiv(EE,16),BT,0,stream>>>(srcS,dstS,qk8,logitE);              // exp(logits)
  mgemm_kernel<64><<<dim3(GB,4),BT,0,stream>>>(x4b,wt+106496,tr_bv,nullptr,nullptr,v8,256,0,1,
                                               nullptr,nullptr,nullptr,nullptr);   // v fp8
  mgemm_kernel<64><<<dim3(GB,1),BT,0,stream>>>(x4b,wt+122880,tr_bs,skipf,nullptr,nullptr,64,0,0,
                                               nullptr,nullptr,nullptr,nullptr);   // skip f32
  tr_pass2_kernel<<<GW,BT,0,stream>>>(rowptr,srcS,logitE,v8,skipf,x5b);
  // ---- EdgeConv ----
  mgemm_kernel<64><<<dim3(GB,2),BT,0,stream>>>(x5b,wt+126976,bPQ,nullptr,nullptr,PQ8,64,0,2,
                                               nullptr,nullptr,nullptr,nullptr);
  edgeconv3_kernel<<<EE/64,BT,0,stream>>>(PQ8,srcS,dstS,wt+135168,ec_b2,(unsigned*)nb5);
  // ---- pool + MLP ----
  pool_kernel<<<cdiv(NN,200),BT,0,stream>>>((unsigned*)nb5,batch,pooled);
  final_kernel<<<1,BT,0,stream>>>(pooled,batch,fc1_W,fc1_b,fc2_W,fc2_b,(float*)d_out);
}